// Round 9
// baseline (2031.740 us; speedup 1.0000x reference)
//
#include <hip/hip_runtime.h>
#include <hip/hip_bf16.h>
#include <math.h>

// Problem constants (from reference)
#define NN 100000
#define FF 512
#define HH 256
#define CC 64
#define KHOPS 10
#define BN_EPS 1e-5f
#define SUBX (NN * 16)  // ushorts per channel-split sub-array (16 ch)

typedef __bf16 bf16x8 __attribute__((ext_vector_type(8)));
typedef float f32x4 __attribute__((ext_vector_type(4)));
typedef unsigned short ushort8v __attribute__((ext_vector_type(8)));

__device__ __forceinline__ unsigned short f2bf(float f) {
    __bf16 b = (__bf16)f;  // v_cvt RNE
    return __builtin_bit_cast(unsigned short, b);
}
__device__ __forceinline__ float bf2f(unsigned short h) {
    unsigned u = ((unsigned)h) << 16;
    return __builtin_bit_cast(float, u);
}
__device__ __forceinline__ float lo16(unsigned u) { return bf2f((unsigned short)(u & 0xFFFF)); }
__device__ __forceinline__ float hi16(unsigned u) { return bf2f((unsigned short)(u >> 16)); }
__device__ __forceinline__ unsigned pk(float a, float b) {
    return ((unsigned)f2bf(b) << 16) | (unsigned)f2bf(a);
}

// async global->LDS, 16B per lane.
typedef __attribute__((address_space(1))) const void g_void;
typedef __attribute__((address_space(3))) void l_void;
__device__ __forceinline__ void gl2lds16(const void* g, void* l) {
    __builtin_amdgcn_global_load_lds((g_void*)g, (l_void*)l, 16, 0, 0);
}

template <int N>
__device__ __forceinline__ void waitcnt_vm() {
    if constexpr (N == 0) asm volatile("s_waitcnt vmcnt(0)" ::: "memory");
    else if constexpr (N == 1) asm volatile("s_waitcnt vmcnt(1)" ::: "memory");
    else if constexpr (N == 2) asm volatile("s_waitcnt vmcnt(2)" ::: "memory");
    else if constexpr (N == 3) asm volatile("s_waitcnt vmcnt(3)" ::: "memory");
    else if constexpr (N == 4) asm volatile("s_waitcnt vmcnt(4)" ::: "memory");
    else if constexpr (N == 5) asm volatile("s_waitcnt vmcnt(5)" ::: "memory");
    else if constexpr (N == 6) asm volatile("s_waitcnt vmcnt(6)" ::: "memory");
    else asm volatile("s_waitcnt vmcnt(8)" ::: "memory");
}

// ---------------- utility kernels ----------------
__global__ void k_zero(float* p, int n) {
    int i = blockIdx.x * blockDim.x + threadIdx.x;
    if (i < n) p[i] = 0.f;
}

__global__ void k_deg_init(int* deg, int n) {
    int i = blockIdx.x * blockDim.x + threadIdx.x;
    if (i < n) deg[i] = 1;  // self-loop
}

__global__ void k_deg_count(const int* __restrict__ dst, int e, int* deg) {
    for (int i = blockIdx.x * blockDim.x + threadIdx.x; i < e; i += gridDim.x * blockDim.x)
        atomicAdd(&deg[dst[i]], 1);
}

__global__ void k_dis(const int* __restrict__ deg, float* dis, int n) {
    int i = blockIdx.x * blockDim.x + threadIdx.x;
    if (i < n) dis[i] = rsqrtf((float)deg[i]);
}

// ---------------- hierarchical scan: offs = exclusive prefix of (deg-1) ----------------
#define SCAN_B 1024
#define SCAN_NB ((NN + SCAN_B - 1) / SCAN_B)  // 98

__global__ void k_scan1(const int* __restrict__ deg, int* __restrict__ part, int n) {
    __shared__ int ls[SCAN_B];
    int i = blockIdx.x * SCAN_B + threadIdx.x;
    ls[threadIdx.x] = (i < n) ? deg[i] - 1 : 0;
    __syncthreads();
    for (int d = SCAN_B / 2; d > 0; d >>= 1) {
        if (threadIdx.x < d) ls[threadIdx.x] += ls[threadIdx.x + d];
        __syncthreads();
    }
    if (threadIdx.x == 0) part[blockIdx.x] = ls[0];
}

__global__ void k_scan2(int* part, int* offs_last, int nb) {
    if (threadIdx.x == 0) {
        int run = 0;
        for (int b = 0; b < nb; b++) { int v = part[b]; part[b] = run; run += v; }
        offs_last[0] = run;  // == E
    }
}

__global__ void k_scan3(const int* __restrict__ deg, const int* __restrict__ part,
                        int* __restrict__ offs, int* __restrict__ cur, int n) {
    __shared__ int ls[SCAN_B];
    int i = blockIdx.x * SCAN_B + threadIdx.x;
    int v = (i < n) ? deg[i] - 1 : 0;
    ls[threadIdx.x] = v;
    __syncthreads();
    for (int d = 1; d < SCAN_B; d <<= 1) {
        int t = (threadIdx.x >= d) ? ls[threadIdx.x - d] : 0;
        __syncthreads();
        ls[threadIdx.x] += t;
        __syncthreads();
    }
    if (i < n) {
        int ex = part[blockIdx.x] + ls[threadIdx.x] - v;
        offs[i] = ex;
        cur[i] = ex;
    }
}

__global__ void k_fill(const int* __restrict__ src, const int* __restrict__ dst, int e,
                       int* cursor, int* __restrict__ csrc) {
    for (int i = blockIdx.x * blockDim.x + threadIdx.x; i < e; i += gridDim.x * blockDim.x) {
        int d = dst[i];
        int s = src[i];
        int p = atomicAdd(&cursor[d], 1);
        csrc[p] = s;
    }
}

// transpose+cast weights: Wt[n*K+k] = bf16(W[k*N+n])
__global__ void k_wt(const float* __restrict__ W, unsigned short* __restrict__ Wt,
                     int K, int N) {
    int i = blockIdx.x * blockDim.x + threadIdx.x;
    if (i < K * N) {
        int n = i / K;
        int k = i - n * K;
        Wt[i] = f2bf(W[(size_t)k * N + n]);
    }
}

// ---------------- bf16 MFMA GEMM, pipelined global_load_lds staging -------------
// C = act(A) @ Bt^T + bias.  BM=128, BK=32. Double-buffered LDS; stage(t+2)
// issued after the read-barrier; raw s_barrier + manual counted vmcnt(S) keeps
// stage(t+1) in flight across both barriers. FUSEBN applies per-K scale/shift
// + ReLU to A fragments. SPLIT writes C in channel-split layout scaled by dis
// (z0 = dis * logits).
template <int AF32, int BN_, int STATS, int NW, int FUSEBN, int SPLIT>
__global__ __launch_bounds__(NW * 64) void k_gemm_mfma(
    const void* __restrict__ Av, const unsigned short* __restrict__ Bt,
    const float* __restrict__ bias, unsigned short* __restrict__ Cb,
    const float* __restrict__ bnscale, const float* __restrict__ bnshift,
    const float* __restrict__ disp,
    float* __restrict__ sum, float* __restrict__ sumsq,
    int M, int K, int Nd) {
    constexpr int NT = NW * 64;
    constexpr int WC = (NW == 8) ? 4 : 2;
    constexpr int PWN = BN_ / WC;
    constexpr int NREP = PWN / 16;
    constexpr int ACH = AF32 ? 8 : 4;
    constexpr int AOPS = 128 * ACH / NT;
    constexpr int BOPS = BN_ * 4 / NT;
    constexpr int S = AOPS + BOPS;  // stage ops per thread
    constexpr int ABUF = AF32 ? 16384 : 8192;
    __shared__ __align__(16) unsigned char Asb[2][ABUF];
    __shared__ __align__(16) unsigned char Bsb[2][BN_ * 64];
    const int tid = threadIdx.x;
    const int lane = tid & 63;
    const int wid = tid >> 6;
    const int wrow = wid / WC, wcol = wid % WC;
    const int row_base = blockIdx.y * 128;
    const int col_base = blockIdx.x * BN_;
    const unsigned char* Abase = (const unsigned char*)Av;
    const size_t arowb = (size_t)K * (AF32 ? 4 : 2);

    f32x4 acc[4][NREP];
#pragma unroll
    for (int m = 0; m < 4; m++)
#pragma unroll
        for (int n = 0; n < NREP; n++)
#pragma unroll
            for (int j = 0; j < 4; j++) acc[m][n][j] = 0.f;

    auto stage = [&](int kt, int buf) {
#pragma unroll
        for (int i = 0; i < AOPS; ++i) {
            int e = i * NT + tid;
            int r = e / ACH;
            int c = e % ACH;
            int cs = AF32 ? (c ^ (r & 7)) : (c ^ ((r >> 1) & 3));
            int grow = row_base + r;
            if (grow > M - 1) grow = M - 1;
            const void* g = Abase + (size_t)grow * arowb + (size_t)kt * (AF32 ? 4 : 2) + (cs << 4);
            gl2lds16(g, Asb[buf] + e * 16);
        }
#pragma unroll
        for (int i = 0; i < BOPS; ++i) {
            int e = i * NT + tid;
            int r = e >> 2, c = e & 3;
            int cs = c ^ ((r >> 1) & 3);
            const void* g = (const unsigned char*)Bt + (size_t)(col_base + r) * (K * 2) +
                            (size_t)kt * 2 + (cs << 4);
            gl2lds16(g, Bsb[buf] + e * 16);
        }
    };

    const int nt = K / 32;
    stage(0, 0);
    if (nt > 1) stage(32, 1);

    for (int t = 0; t < nt; ++t) {
        if (t + 1 < nt) waitcnt_vm<S>();   // stage(t) done; stage(t+1) in flight
        else            waitcnt_vm<0>();
        __builtin_amdgcn_s_barrier();
        const int cur = t & 1;

        f32x4 sc0{}, sc1{}, sh0{}, sh1{};
        if (FUSEBN) {
            int kc = t * 32 + (lane >> 4) * 8;
            sc0 = *(const f32x4*)(bnscale + kc);
            sc1 = *(const f32x4*)(bnscale + kc + 4);
            sh0 = *(const f32x4*)(bnshift + kc);
            sh1 = *(const f32x4*)(bnshift + kc + 4);
        }

        bf16x8 af[4], bfr[NREP];
#pragma unroll
        for (int m = 0; m < 4; ++m) {
            int r = wrow * 64 + m * 16 + (lane & 15);
            if (AF32) {
                int x7 = r & 7;
                int q2 = (lane >> 4) * 2;
                f32x4 f0 = *(const f32x4*)(Asb[cur] + r * 128 + ((q2 ^ x7) << 4));
                f32x4 f1 = *(const f32x4*)(Asb[cur] + r * 128 + (((q2 + 1) ^ x7) << 4));
                bf16x8 a;
                a[0] = (__bf16)f0[0]; a[1] = (__bf16)f0[1]; a[2] = (__bf16)f0[2]; a[3] = (__bf16)f0[3];
                a[4] = (__bf16)f1[0]; a[5] = (__bf16)f1[1]; a[6] = (__bf16)f1[2]; a[7] = (__bf16)f1[3];
                af[m] = a;
            } else {
                int cs = (lane >> 4) ^ ((r >> 1) & 3);
                bf16x8 a = *(const bf16x8*)(Asb[cur] + r * 64 + (cs << 4));
                if (FUSEBN) {
#pragma unroll
                    for (int j = 0; j < 4; ++j) {
                        a[j]     = (__bf16)fmaxf((float)a[j]     * sc0[j] + sh0[j], 0.f);
                        a[j + 4] = (__bf16)fmaxf((float)a[j + 4] * sc1[j] + sh1[j], 0.f);
                    }
                }
                af[m] = a;
            }
        }
#pragma unroll
        for (int n = 0; n < NREP; ++n) {
            int r = wcol * PWN + n * 16 + (lane & 15);
            int cs = (lane >> 4) ^ ((r >> 1) & 3);
            bfr[n] = *(const bf16x8*)(Bsb[cur] + r * 64 + (cs << 4));
        }
#pragma unroll
        for (int m = 0; m < 4; ++m)
#pragma unroll
            for (int n = 0; n < NREP; ++n)
                acc[m][n] = __builtin_amdgcn_mfma_f32_16x16x32_bf16(af[m], bfr[n], acc[m][n], 0, 0, 0);

        __builtin_amdgcn_s_barrier();      // all waves done reading buf[cur]
        if (t + 2 < nt) stage((t + 2) * 32, cur);
    }

    // epilogue: C/D mapping col=lane&15, row=(lane>>4)*4+j
    const int lc = lane & 15;
    const int lr = (lane >> 4) * 4;
#pragma unroll
    for (int m = 0; m < 4; ++m) {
        int gr0 = row_base + wrow * 64 + m * 16 + lr;
#pragma unroll
        for (int n = 0; n < NREP; ++n) {
            int gc = col_base + wcol * PWN + n * 16 + lc;
            float bb = bias[gc];
#pragma unroll
            for (int j = 0; j < 4; ++j) {
                int gr = gr0 + j;
                if (gr < M) {
                    float v = acc[m][n][j] + bb;
                    if (SPLIT) {
                        v *= disp[gr];  // z0 = dis * logits
                        Cb[(size_t)(gc >> 4) * SUBX + (size_t)gr * 16 + (gc & 15)] = f2bf(v);
                    } else {
                        Cb[(size_t)gr * Nd + gc] = f2bf(v);
                    }
                }
            }
        }
    }
    if (STATS) {
#pragma unroll
        for (int n = 0; n < NREP; ++n) {
            int gc = col_base + wcol * PWN + n * 16 + lc;
            float bb = bias[gc];
            float s = 0.f, s2 = 0.f;
#pragma unroll
            for (int m = 0; m < 4; ++m) {
                int gr0 = row_base + wrow * 64 + m * 16 + lr;
#pragma unroll
                for (int j = 0; j < 4; ++j) {
                    if (gr0 + j < M) {
                        float v = acc[m][n][j] + bb;
                        s += v;
                        s2 += v * v;
                    }
                }
            }
            s += __shfl_xor(s, 16); s += __shfl_xor(s, 32);
            s2 += __shfl_xor(s2, 16); s2 += __shfl_xor(s2, 32);
            if ((lane >> 4) == 0) {
                atomicAdd(&sum[gc], s);
                atomicAdd(&sumsq[gc], s2);
            }
        }
    }
}

__global__ void k_bnfin(const float* __restrict__ sum, const float* __restrict__ sq,
                        const float* __restrict__ g, const float* __restrict__ be,
                        float* scale, float* shift) {
    int c = threadIdx.x;
    float mu = sum[c] * (1.f / NN);
    float var = sq[c] * (1.f / NN) - mu * mu;
    float sc = g[c] * rsqrtf(var + BN_EPS);
    scale[c] = sc;
    shift[c] = be[c] - mu * sc;
}

// ---------------- propagation: channel-split quarter, SEQUENTIAL passes -------
// z-form: z_{k+1}[d] = dis2[d] * (z_k[d] + sum_{s in N(d)} z_k[s]); no edge
// weights needed. One quarter (16 ch, 3.2 MB) per kernel launch -> gather set
// is L2-resident on every XCD. Wave = 1 node: 16 groups of 4 lanes; group g
// takes every-16th neighbor; lane reads uint2 (4 ch). csrc nontemporal.
__global__ __launch_bounds__(256) void k_hopq(
    const unsigned short* __restrict__ zin, unsigned short* __restrict__ zout,
    const int* __restrict__ offs, const int* __restrict__ csrc,
    const float* __restrict__ dis, int n) {
    int wid = (int)((blockIdx.x * (size_t)blockDim.x + threadIdx.x) >> 6);
    if (wid >= n) return;
    int lane = threadIdx.x & 63;
    int g = lane >> 2;   // group 0..15
    int j = lane & 3;    // uint2 slot in 32B row
    const uint2* zi = (const uint2*)zin;  // row = 4 uint2 (16 bf16)
    float y0 = 0.f, y1 = 0.f, y2 = 0.f, y3 = 0.f;
    if (g == 0) {  // self term
        uint2 v = zi[(size_t)wid * 4 + j];
        y0 = lo16(v.x); y1 = hi16(v.x);
        y2 = lo16(v.y); y3 = hi16(v.y);
    }
    int p0 = offs[wid], p1 = offs[wid + 1];
    int p = p0 + g;
    for (; p + 16 < p1; p += 32) {  // 2-deep unroll
        int sA = __builtin_nontemporal_load(&csrc[p]);
        int sB = __builtin_nontemporal_load(&csrc[p + 16]);
        uint2 vA = zi[(size_t)sA * 4 + j];
        uint2 vB = zi[(size_t)sB * 4 + j];
        y0 += lo16(vA.x); y1 += hi16(vA.x);
        y2 += lo16(vA.y); y3 += hi16(vA.y);
        y0 += lo16(vB.x); y1 += hi16(vB.x);
        y2 += lo16(vB.y); y3 += hi16(vB.y);
    }
    for (; p < p1; p += 16) {
        int s = __builtin_nontemporal_load(&csrc[p]);
        uint2 v = zi[(size_t)s * 4 + j];
        y0 += lo16(v.x); y1 += hi16(v.x);
        y2 += lo16(v.y); y3 += hi16(v.y);
    }
    // reduce across the 16 groups (lane bits 2..5)
#pragma unroll
    for (int m = 4; m <= 32; m <<= 1) {
        y0 += __shfl_xor(y0, m); y1 += __shfl_xor(y1, m);
        y2 += __shfl_xor(y2, m); y3 += __shfl_xor(y3, m);
    }
    if (g == 0) {
        float dn = dis[wid];
        float d2 = dn * dn;
        uint2 r;
        r.x = pk(d2 * y0, d2 * y1);
        r.y = pk(d2 * y2, d2 * y3);
        ((uint2*)zout)[(size_t)wid * 4 + j] = r;
    }
}

struct XPack { const unsigned short* p[KHOPS + 1]; };

// two nodes per wave (one per 32-lane half); channel-split z inputs; x = z/dis.
__global__ void k_finprop(XPack xp, const float* __restrict__ pw,
                          const float* __restrict__ pbp, const float* __restrict__ dis,
                          float* __restrict__ out, int n) {
    int gw = (int)((blockIdx.x * (size_t)blockDim.x + threadIdx.x) >> 6);
    int lane = threadIdx.x & 63;
    int hf = lane >> 5;
    int l = lane & 31;
    int node = gw * 2 + hf;
    if (node >= n) return;
    float pw0 = pw[2 * l], pw1 = pw[2 * l + 1];
    float pb0 = pbp[0];
    float invd = 1.f / dis[node];
    size_t idx = (size_t)(l >> 3) * (SUBX / 2) + (size_t)node * 8 + (l & 7);
    float o0 = 0.f, o1 = 0.f;
#pragma unroll
    for (int k = 0; k <= KHOPS; k++) {
        unsigned v = ((const unsigned*)xp.p[k])[idx];
        float v0 = lo16(v);
        float v1 = hi16(v);
        float d = v0 * pw0 + v1 * pw1;
#pragma unroll
        for (int m = 16; m >= 1; m >>= 1) d += __shfl_xor(d, m);
        float s = 1.f / (1.f + expf(-(d * invd + pb0)));  // x_k . pw = invd * (z_k . pw)
        o0 += s * v0;
        o1 += s * v1;
    }
    o0 *= invd;  // back to x-space
    o1 *= invd;
    float mx = fmaxf(o0, o1);
#pragma unroll
    for (int m = 16; m >= 1; m >>= 1) mx = fmaxf(mx, __shfl_xor(mx, m));
    float e = expf(o0 - mx) + expf(o1 - mx);
#pragma unroll
    for (int m = 16; m >= 1; m >>= 1) e += __shfl_xor(e, m);
    float lg = mx + logf(e);
    float2 r = make_float2(o0 - lg, o1 - lg);
    *(float2*)(out + (size_t)node * 64 + 2 * l) = r;
}

// ---------------- launch ----------------
extern "C" void kernel_launch(void* const* d_in, const int* in_sizes, int n_in,
                              void* d_out, int out_size, void* d_ws, size_t ws_size,
                              hipStream_t stream) {
    const float* x  = (const float*)d_in[0];
    const float* W0 = (const float*)d_in[1];
    const float* b0 = (const float*)d_in[2];
    const float* g0 = (const float*)d_in[3];
    const float* be0 = (const float*)d_in[4];
    const float* W1 = (const float*)d_in[5];
    const float* b1 = (const float*)d_in[6];
    const float* g1 = (const float*)d_in[7];
    const float* be1 = (const float*)d_in[8];
    const float* W2 = (const float*)d_in[9];
    const float* b2 = (const float*)d_in[10];
    const float* pw = (const float*)d_in[11];
    const float* pb = (const float*)d_in[12];
    const int* ei = (const int*)d_in[13];
    const int E = in_sizes[13] / 2;
    const int* esrc = ei;
    const int* edst = ei + E;

    char* ws = (char*)d_ws;
    const size_t XKB = (size_t)NN * CC * 2;  // 12,800,000 B per hop buffer
    unsigned short* h0b = (unsigned short*)(ws + 0);          // [N,256] bf16 (pre-BN)
    unsigned short* h1b = (unsigned short*)(ws + 51200000);   // [N,256] bf16 (pre-BN)
    unsigned short* xk[KHOPS + 1];  // each: 4 quarters of [N][16] bf16
    xk[0] = (unsigned short*)(ws + 0);                         // over h0b (dead after gemm1)
    xk[5] = (unsigned short*)(ws + XKB);
    xk[6] = (unsigned short*)(ws + 2 * XKB);
    xk[7] = (unsigned short*)(ws + 3 * XKB);
    xk[1] = (unsigned short*)(ws + 51200000);                  // over h1b (dead after gemm2)
    xk[2] = (unsigned short*)(ws + 51200000 + XKB);
    xk[3] = (unsigned short*)(ws + 51200000 + 2 * XKB);
    xk[4] = (unsigned short*)(ws + 51200000 + 3 * XKB);
    xk[8] = (unsigned short*)(ws + 102400000);
    xk[9] = (unsigned short*)(ws + 115200000);
    xk[10] = (unsigned short*)(ws + 128000000);

    int*   deg  = (int*)  (ws + 140800000);
    float* dis  = (float*)(ws + 141200000);
    int*   offs = (int*)  (ws + 141600000);   // NN+1 ints
    int*   cur  = (int*)  (ws + 142000064);
    int*   csrc = (int*)  (ws + 142400064);
    float* stats = (float*)(ws + 155200064);  // 2048 f32
    int*   part = (int*)  (ws + 155208256);   // scan partials
    unsigned short* W0t = (unsigned short*)(ws + 155209280);  // [256,512]
    unsigned short* W1t = (unsigned short*)(ws + 155471424);  // [256,256]
    unsigned short* W2t = (unsigned short*)(ws + 155602496);  // [64,256]

    float* sum0 = stats,        *sq0 = stats + 256;
    float* sum1 = stats + 512,  *sq1 = stats + 768;
    float* scale0 = stats + 1024, *shift0 = stats + 1280;
    float* scale1 = stats + 1536, *shift1 = stats + 1792;

    float* out = (float*)d_out;

    const int TPB = 256;
    int ngrid = (NN + TPB - 1) / TPB;
    int egrid = (E + TPB - 1) / TPB;
    int wgrid = (NN * 64 + TPB - 1) / TPB;               // one wave per node
    int wgrid2 = (((NN + 1) / 2) * 64 + TPB - 1) / TPB;  // two nodes per wave
    int mtiles = (NN + 127) / 128;                       // 782

    // graph preprocessing
    k_zero<<<2, 1024, 0, stream>>>(stats, 2048);
    k_deg_init<<<ngrid, TPB, 0, stream>>>(deg, NN);
    k_deg_count<<<egrid, TPB, 0, stream>>>(edst, E, deg);
    k_dis<<<ngrid, TPB, 0, stream>>>(deg, dis, NN);
    k_scan1<<<SCAN_NB, SCAN_B, 0, stream>>>(deg, part, NN);
    k_scan2<<<1, 64, 0, stream>>>(part, offs + NN, SCAN_NB);
    k_scan3<<<SCAN_NB, SCAN_B, 0, stream>>>(deg, part, offs, cur, NN);
    k_fill<<<egrid, TPB, 0, stream>>>(esrc, edst, E, cur, csrc);

    // weight transpose+cast (tiny)
    k_wt<<<(FF * HH + TPB - 1) / TPB, TPB, 0, stream>>>(W0, W0t, FF, HH);
    k_wt<<<(HH * HH + TPB - 1) / TPB, TPB, 0, stream>>>(W1, W1t, HH, HH);
    k_wt<<<(HH * CC + TPB - 1) / TPB, TPB, 0, stream>>>(W2, W2t, HH, CC);

    // layer 0: x(f32) @ W0 -> h0b (pre-BN bf16) + stats0
    k_gemm_mfma<1, 256, 1, 8, 0, 0><<<dim3(1, mtiles), 512, 0, stream>>>(
        x, W0t, b0, h0b, nullptr, nullptr, nullptr, sum0, sq0, NN, FF, HH);
    k_bnfin<<<1, 256, 0, stream>>>(sum0, sq0, g0, be0, scale0, shift0);

    // layer 1: BN0+ReLU(h0b) @ W1 -> h1b (pre-BN bf16) + stats1 (BN fused in A-read)
    k_gemm_mfma<0, 256, 1, 8, 1, 0><<<dim3(1, mtiles), 512, 0, stream>>>(
        h0b, W1t, b1, h1b, scale0, shift0, nullptr, sum1, sq1, NN, HH, HH);
    k_bnfin<<<1, 256, 0, stream>>>(sum1, sq1, g1, be1, scale1, shift1);

    // layer 2: BN1+ReLU(h1b) @ W2 -> z0 = dis*logits (bf16, channel-split)
    k_gemm_mfma<0, 64, 0, 4, 1, 1><<<dim3(1, mtiles), 256, 0, stream>>>(
        h1b, W2t, b2, xk[0], scale1, shift1, dis, nullptr, nullptr, NN, HH, CC);

    // propagation: z_{k+1} = dis2 * (z_k + A z_k), 4 sequential quarter passes/hop
    for (int k = 0; k < KHOPS; k++)
        for (int q = 0; q < 4; q++)
            k_hopq<<<wgrid, TPB, 0, stream>>>(xk[k] + (size_t)q * SUBX,
                                              xk[k + 1] + (size_t)q * SUBX,
                                              offs, csrc, dis, NN);

    // fused score + weighted-sum + log-softmax (x_k = z_k / dis)
    XPack xp;
    for (int k = 0; k <= KHOPS; k++) xp.p[k] = xk[k];
    k_finprop<<<wgrid2, TPB, 0, stream>>>(xp, pw, pb, dis, out, NN);
}

// Round 10
// 1084.844 us; speedup vs baseline: 1.8728x; 1.8728x over previous
//
#include <hip/hip_runtime.h>
#include <hip/hip_bf16.h>
#include <math.h>

// Problem constants (from reference)
#define NN 100000
#define FF 512
#define HH 256
#define CC 64
#define KHOPS 10
#define BN_EPS 1e-5f
#define NPART 8
#define DRANGE ((NN + NPART - 1) / NPART)  // 12500 dsts per XCD partition

typedef __bf16 bf16x8 __attribute__((ext_vector_type(8)));
typedef float f32x4 __attribute__((ext_vector_type(4)));
typedef unsigned short ushort8v __attribute__((ext_vector_type(8)));

__device__ __forceinline__ unsigned short f2bf(float f) {
    __bf16 b = (__bf16)f;  // v_cvt RNE
    return __builtin_bit_cast(unsigned short, b);
}
__device__ __forceinline__ float bf2f(unsigned short h) {
    unsigned u = ((unsigned)h) << 16;
    return __builtin_bit_cast(float, u);
}
__device__ __forceinline__ float lo16(unsigned u) { return bf2f((unsigned short)(u & 0xFFFF)); }
__device__ __forceinline__ float hi16(unsigned u) { return bf2f((unsigned short)(u >> 16)); }
__device__ __forceinline__ unsigned pk(float a, float b) {
    return ((unsigned)f2bf(b) << 16) | (unsigned)f2bf(a);
}

// async global->LDS, 16B per lane.
typedef __attribute__((address_space(1))) const void g_void;
typedef __attribute__((address_space(3))) void l_void;
__device__ __forceinline__ void gl2lds16(const void* g, void* l) {
    __builtin_amdgcn_global_load_lds((g_void*)g, (l_void*)l, 16, 0, 0);
}

template <int N>
__device__ __forceinline__ void waitcnt_vm() {
    if constexpr (N == 0) asm volatile("s_waitcnt vmcnt(0)" ::: "memory");
    else if constexpr (N == 1) asm volatile("s_waitcnt vmcnt(1)" ::: "memory");
    else if constexpr (N == 2) asm volatile("s_waitcnt vmcnt(2)" ::: "memory");
    else if constexpr (N == 3) asm volatile("s_waitcnt vmcnt(3)" ::: "memory");
    else if constexpr (N == 4) asm volatile("s_waitcnt vmcnt(4)" ::: "memory");
    else if constexpr (N == 5) asm volatile("s_waitcnt vmcnt(5)" ::: "memory");
    else if constexpr (N == 6) asm volatile("s_waitcnt vmcnt(6)" ::: "memory");
    else asm volatile("s_waitcnt vmcnt(8)" ::: "memory");
}

// ---------------- utility kernels ----------------
__global__ void k_zero(float* p, int n) {
    int i = blockIdx.x * blockDim.x + threadIdx.x;
    if (i < n) p[i] = 0.f;
}

__global__ void k_deg_init(int* deg, int n) {
    int i = blockIdx.x * blockDim.x + threadIdx.x;
    if (i < n) deg[i] = 1;  // self-loop
}

// XCD-partitioned degree count: blocks with blockIdx%8==p (XCD p) histogram
// dst range [p*DRANGE,(p+1)*DRANGE) in LDS, then flush to XCD-local deg lines.
__global__ __launch_bounds__(256) void k_deg_part(const int* __restrict__ dst, int e,
                                                  int* __restrict__ deg) {
    __shared__ int hist[DRANGE];  // 50 KB
    int part = blockIdx.x & 7;
    int lo = part * DRANGE;
    int range = min(DRANGE, NN - lo);
    for (int i = threadIdx.x; i < range; i += blockDim.x) hist[i] = 0;
    __syncthreads();
    int nsub = gridDim.x >> 3, sub = blockIdx.x >> 3;
    for (int i = sub * blockDim.x + threadIdx.x; i < e; i += nsub * blockDim.x) {
        int d = dst[i] - lo;
        if ((unsigned)d < (unsigned)range) atomicAdd(&hist[d], 1);
    }
    __syncthreads();
    for (int i = threadIdx.x; i < range; i += blockDim.x) {
        int v = hist[i];
        if (v) atomicAdd(&deg[lo + i], v);
    }
}

__global__ void k_dis(const int* __restrict__ deg, float* dis, int n) {
    int i = blockIdx.x * blockDim.x + threadIdx.x;
    if (i < n) dis[i] = rsqrtf((float)deg[i]);
}

// ---------------- hierarchical scan: offs = exclusive prefix of (deg-1) ----------------
#define SCAN_B 1024
#define SCAN_NB ((NN + SCAN_B - 1) / SCAN_B)  // 98

__global__ void k_scan1(const int* __restrict__ deg, int* __restrict__ part, int n) {
    __shared__ int ls[SCAN_B];
    int i = blockIdx.x * SCAN_B + threadIdx.x;
    ls[threadIdx.x] = (i < n) ? deg[i] - 1 : 0;
    __syncthreads();
    for (int d = SCAN_B / 2; d > 0; d >>= 1) {
        if (threadIdx.x < d) ls[threadIdx.x] += ls[threadIdx.x + d];
        __syncthreads();
    }
    if (threadIdx.x == 0) part[blockIdx.x] = ls[0];
}

__global__ void k_scan2(int* part, int* offs_last, int nb) {
    if (threadIdx.x == 0) {
        int run = 0;
        for (int b = 0; b < nb; b++) { int v = part[b]; part[b] = run; run += v; }
        offs_last[0] = run;  // == E
    }
}

__global__ void k_scan3(const int* __restrict__ deg, const int* __restrict__ part,
                        int* __restrict__ offs, int* __restrict__ cur, int n) {
    __shared__ int ls[SCAN_B];
    int i = blockIdx.x * SCAN_B + threadIdx.x;
    int v = (i < n) ? deg[i] - 1 : 0;
    ls[threadIdx.x] = v;
    __syncthreads();
    for (int d = 1; d < SCAN_B; d <<= 1) {
        int t = (threadIdx.x >= d) ? ls[threadIdx.x - d] : 0;
        __syncthreads();
        ls[threadIdx.x] += t;
        __syncthreads();
    }
    if (i < n) {
        int ex = part[blockIdx.x] + ls[threadIdx.x] - v;
        offs[i] = ex;
        cur[i] = ex;
    }
}

// XCD-partitioned CSR fill: blocks on XCD p handle dst range p -> cursor
// atomics + csrc writes stay in one L2 (no cross-XCD line ping-pong).
__global__ __launch_bounds__(256) void k_fill_part(
    const int* __restrict__ src, const int* __restrict__ dst, int e,
    int* __restrict__ cursor, int* __restrict__ csrc) {
    int part = blockIdx.x & 7;
    int lo = part * DRANGE;
    int range = min(DRANGE, NN - lo);
    int nsub = gridDim.x >> 3, sub = blockIdx.x >> 3;
    for (int i = sub * blockDim.x + threadIdx.x; i < e; i += nsub * blockDim.x) {
        int d = dst[i];
        int dl = d - lo;
        if ((unsigned)dl < (unsigned)range) {
            int p = atomicAdd(&cursor[d], 1);
            csrc[p] = src[i];
        }
    }
}

// transpose+cast weights: Wt[n*K+k] = bf16(W[k*N+n])
__global__ void k_wt(const float* __restrict__ W, unsigned short* __restrict__ Wt,
                     int K, int N) {
    int i = blockIdx.x * blockDim.x + threadIdx.x;
    if (i < K * N) {
        int n = i / K;
        int k = i - n * K;
        Wt[i] = f2bf(W[(size_t)k * N + n]);
    }
}

// ---------------- bf16 MFMA GEMM, pipelined global_load_lds staging -------------
// C = act(A) @ Bt^T + bias.  BM=128, BK=32. Double-buffered LDS; stage(t+2)
// issued after the read-barrier; raw s_barrier + counted vmcnt(S) keeps
// stage(t+1) in flight. FUSEBN applies per-K scale/shift + ReLU to A frags.
// ZSCALE multiplies C rows by dis[row] (z0 = dis * logits).
template <int AF32, int BN_, int STATS, int NW, int FUSEBN, int ZSCALE>
__global__ __launch_bounds__(NW * 64) void k_gemm_mfma(
    const void* __restrict__ Av, const unsigned short* __restrict__ Bt,
    const float* __restrict__ bias, unsigned short* __restrict__ Cb,
    const float* __restrict__ bnscale, const float* __restrict__ bnshift,
    const float* __restrict__ disp,
    float* __restrict__ sum, float* __restrict__ sumsq,
    int M, int K, int Nd) {
    constexpr int NT = NW * 64;
    constexpr int WC = (NW == 8) ? 4 : 2;
    constexpr int PWN = BN_ / WC;
    constexpr int NREP = PWN / 16;
    constexpr int ACH = AF32 ? 8 : 4;
    constexpr int AOPS = 128 * ACH / NT;
    constexpr int BOPS = BN_ * 4 / NT;
    constexpr int S = AOPS + BOPS;  // stage ops per thread
    constexpr int ABUF = AF32 ? 16384 : 8192;
    __shared__ __align__(16) unsigned char Asb[2][ABUF];
    __shared__ __align__(16) unsigned char Bsb[2][BN_ * 64];
    const int tid = threadIdx.x;
    const int lane = tid & 63;
    const int wid = tid >> 6;
    const int wrow = wid / WC, wcol = wid % WC;
    const int row_base = blockIdx.y * 128;
    const int col_base = blockIdx.x * BN_;
    const unsigned char* Abase = (const unsigned char*)Av;
    const size_t arowb = (size_t)K * (AF32 ? 4 : 2);

    f32x4 acc[4][NREP];
#pragma unroll
    for (int m = 0; m < 4; m++)
#pragma unroll
        for (int n = 0; n < NREP; n++)
#pragma unroll
            for (int j = 0; j < 4; j++) acc[m][n][j] = 0.f;

    auto stage = [&](int kt, int buf) {
#pragma unroll
        for (int i = 0; i < AOPS; ++i) {
            int e = i * NT + tid;
            int r = e / ACH;
            int c = e % ACH;
            int cs = AF32 ? (c ^ (r & 7)) : (c ^ ((r >> 1) & 3));
            int grow = row_base + r;
            if (grow > M - 1) grow = M - 1;
            const void* g = Abase + (size_t)grow * arowb + (size_t)kt * (AF32 ? 4 : 2) + (cs << 4);
            gl2lds16(g, Asb[buf] + e * 16);
        }
#pragma unroll
        for (int i = 0; i < BOPS; ++i) {
            int e = i * NT + tid;
            int r = e >> 2, c = e & 3;
            int cs = c ^ ((r >> 1) & 3);
            const void* g = (const unsigned char*)Bt + (size_t)(col_base + r) * (K * 2) +
                            (size_t)kt * 2 + (cs << 4);
            gl2lds16(g, Bsb[buf] + e * 16);
        }
    };

    const int nt = K / 32;
    stage(0, 0);
    if (nt > 1) stage(32, 1);

    for (int t = 0; t < nt; ++t) {
        if (t + 1 < nt) waitcnt_vm<S>();   // stage(t) done; stage(t+1) in flight
        else            waitcnt_vm<0>();
        __builtin_amdgcn_s_barrier();
        const int cur = t & 1;

        f32x4 sc0{}, sc1{}, sh0{}, sh1{};
        if (FUSEBN) {
            int kc = t * 32 + (lane >> 4) * 8;
            sc0 = *(const f32x4*)(bnscale + kc);
            sc1 = *(const f32x4*)(bnscale + kc + 4);
            sh0 = *(const f32x4*)(bnshift + kc);
            sh1 = *(const f32x4*)(bnshift + kc + 4);
        }

        bf16x8 af[4], bfr[NREP];
#pragma unroll
        for (int m = 0; m < 4; ++m) {
            int r = wrow * 64 + m * 16 + (lane & 15);
            if (AF32) {
                int x7 = r & 7;
                int q2 = (lane >> 4) * 2;
                f32x4 f0 = *(const f32x4*)(Asb[cur] + r * 128 + ((q2 ^ x7) << 4));
                f32x4 f1 = *(const f32x4*)(Asb[cur] + r * 128 + (((q2 + 1) ^ x7) << 4));
                bf16x8 a;
                a[0] = (__bf16)f0[0]; a[1] = (__bf16)f0[1]; a[2] = (__bf16)f0[2]; a[3] = (__bf16)f0[3];
                a[4] = (__bf16)f1[0]; a[5] = (__bf16)f1[1]; a[6] = (__bf16)f1[2]; a[7] = (__bf16)f1[3];
                af[m] = a;
            } else {
                int cs = (lane >> 4) ^ ((r >> 1) & 3);
                bf16x8 a = *(const bf16x8*)(Asb[cur] + r * 64 + (cs << 4));
                if (FUSEBN) {
#pragma unroll
                    for (int j = 0; j < 4; ++j) {
                        a[j]     = (__bf16)fmaxf((float)a[j]     * sc0[j] + sh0[j], 0.f);
                        a[j + 4] = (__bf16)fmaxf((float)a[j + 4] * sc1[j] + sh1[j], 0.f);
                    }
                }
                af[m] = a;
            }
        }
#pragma unroll
        for (int n = 0; n < NREP; ++n) {
            int r = wcol * PWN + n * 16 + (lane & 15);
            int cs = (lane >> 4) ^ ((r >> 1) & 3);
            bfr[n] = *(const bf16x8*)(Bsb[cur] + r * 64 + (cs << 4));
        }
#pragma unroll
        for (int m = 0; m < 4; ++m)
#pragma unroll
            for (int n = 0; n < NREP; ++n)
                acc[m][n] = __builtin_amdgcn_mfma_f32_16x16x32_bf16(af[m], bfr[n], acc[m][n], 0, 0, 0);

        __builtin_amdgcn_s_barrier();      // all waves done reading buf[cur]
        if (t + 2 < nt) stage((t + 2) * 32, cur);
    }

    // epilogue: C/D mapping col=lane&15, row=(lane>>4)*4+j
    const int lc = lane & 15;
    const int lr = (lane >> 4) * 4;
#pragma unroll
    for (int m = 0; m < 4; ++m) {
        int gr0 = row_base + wrow * 64 + m * 16 + lr;
#pragma unroll
        for (int n = 0; n < NREP; ++n) {
            int gc = col_base + wcol * PWN + n * 16 + lc;
            float bb = bias[gc];
#pragma unroll
            for (int j = 0; j < 4; ++j) {
                int gr = gr0 + j;
                if (gr < M) {
                    float v = acc[m][n][j] + bb;
                    if (ZSCALE) v *= disp[gr];  // z0 = dis * logits
                    Cb[(size_t)gr * Nd + gc] = f2bf(v);
                }
            }
        }
    }
    if (STATS) {
#pragma unroll
        for (int n = 0; n < NREP; ++n) {
            int gc = col_base + wcol * PWN + n * 16 + lc;
            float bb = bias[gc];
            float s = 0.f, s2 = 0.f;
#pragma unroll
            for (int m = 0; m < 4; ++m) {
                int gr0 = row_base + wrow * 64 + m * 16 + lr;
#pragma unroll
                for (int j = 0; j < 4; ++j) {
                    if (gr0 + j < M) {
                        float v = acc[m][n][j] + bb;
                        s += v;
                        s2 += v * v;
                    }
                }
            }
            s += __shfl_xor(s, 16); s += __shfl_xor(s, 32);
            s2 += __shfl_xor(s2, 16); s2 += __shfl_xor(s2, 32);
            if ((lane >> 4) == 0) {
                atomicAdd(&sum[gc], s);
                atomicAdd(&sumsq[gc], s2);
            }
        }
    }
}

__global__ void k_bnfin(const float* __restrict__ sum, const float* __restrict__ sq,
                        const float* __restrict__ g, const float* __restrict__ be,
                        float* scale, float* shift) {
    int c = threadIdx.x;
    float mu = sum[c] * (1.f / NN);
    float var = sq[c] * (1.f / NN) - mu * mu;
    float sc = g[c] * rsqrtf(var + BN_EPS);
    scale[c] = sc;
    shift[c] = be[c] - mu * sc;
}

// ---------------- propagation (round-6 structure, z-form: no edge weights) ----
// z_{k+1}[d] = dis2[d] * (z_k[d] + sum_{s in N(d)} z_k[s]).
// one wave per node; eight 8-lane groups each take every-8th neighbor with
// uint4 (8-channel) loads -> one load inst = 8 cache lines in flight.
__global__ void k_hop(const unsigned short* __restrict__ zin,
                      unsigned short* __restrict__ zout,
                      const int* __restrict__ offs, const int* __restrict__ csrc,
                      const float* __restrict__ dis, int n) {
    int wid = (int)((blockIdx.x * (size_t)blockDim.x + threadIdx.x) >> 6);
    if (wid >= n) return;
    int lane = threadIdx.x & 63;
    int g = lane >> 3;   // group 0..7
    int j = lane & 7;    // 16B slot in row
    const uint4* z16 = (const uint4*)zin;  // row = 8 uint4 (64 bf16)
    float y0 = 0.f, y1 = 0.f, y2 = 0.f, y3 = 0.f, y4 = 0.f, y5 = 0.f, y6 = 0.f, y7 = 0.f;
    if (g == 0) {  // self term z_k[d]
        uint4 v = z16[(size_t)wid * 8 + j];
        y0 = lo16(v.x); y1 = hi16(v.x);
        y2 = lo16(v.y); y3 = hi16(v.y);
        y4 = lo16(v.z); y5 = hi16(v.z);
        y6 = lo16(v.w); y7 = hi16(v.w);
    }
    int p0 = offs[wid], p1 = offs[wid + 1];
    int p = p0 + g;
    for (; p + 8 < p1; p += 16) {
        int sA = __builtin_nontemporal_load(&csrc[p]);
        int sB = __builtin_nontemporal_load(&csrc[p + 8]);
        uint4 vA = z16[(size_t)sA * 8 + j];
        uint4 vB = z16[(size_t)sB * 8 + j];
        y0 += lo16(vA.x); y1 += hi16(vA.x);
        y2 += lo16(vA.y); y3 += hi16(vA.y);
        y4 += lo16(vA.z); y5 += hi16(vA.z);
        y6 += lo16(vA.w); y7 += hi16(vA.w);
        y0 += lo16(vB.x); y1 += hi16(vB.x);
        y2 += lo16(vB.y); y3 += hi16(vB.y);
        y4 += lo16(vB.z); y5 += hi16(vB.z);
        y6 += lo16(vB.w); y7 += hi16(vB.w);
    }
    for (; p < p1; p += 8) {
        int s = __builtin_nontemporal_load(&csrc[p]);
        uint4 v = z16[(size_t)s * 8 + j];
        y0 += lo16(v.x); y1 += hi16(v.x);
        y2 += lo16(v.y); y3 += hi16(v.y);
        y4 += lo16(v.z); y5 += hi16(v.z);
        y6 += lo16(v.w); y7 += hi16(v.w);
    }
    // sum across the 8 groups (lane bits 3..5)
#pragma unroll
    for (int m = 8; m <= 32; m <<= 1) {
        y0 += __shfl_xor(y0, m); y1 += __shfl_xor(y1, m);
        y2 += __shfl_xor(y2, m); y3 += __shfl_xor(y3, m);
        y4 += __shfl_xor(y4, m); y5 += __shfl_xor(y5, m);
        y6 += __shfl_xor(y6, m); y7 += __shfl_xor(y7, m);
    }
    if (g == 0) {
        float dn = dis[wid];
        float d2 = dn * dn;
        uint4 r;
        r.x = pk(d2 * y0, d2 * y1); r.y = pk(d2 * y2, d2 * y3);
        r.z = pk(d2 * y4, d2 * y5); r.w = pk(d2 * y6, d2 * y7);
        ((uint4*)zout)[(size_t)wid * 8 + j] = r;
    }
}

struct XPack { const unsigned short* p[KHOPS + 1]; };

// two nodes per wave (one per 32-lane half); z inputs, x = z/dis.
__global__ void k_finprop(XPack xp, const float* __restrict__ pw,
                          const float* __restrict__ pbp, const float* __restrict__ dis,
                          float* __restrict__ out, int n) {
    int gw = (int)((blockIdx.x * (size_t)blockDim.x + threadIdx.x) >> 6);
    int lane = threadIdx.x & 63;
    int hf = lane >> 5;
    int l = lane & 31;
    int node = gw * 2 + hf;
    if (node >= n) return;
    float pw0 = pw[2 * l], pw1 = pw[2 * l + 1];
    float pb0 = pbp[0];
    float invd = 1.f / dis[node];
    float o0 = 0.f, o1 = 0.f;
#pragma unroll
    for (int k = 0; k <= KHOPS; k++) {
        unsigned v = ((const unsigned*)xp.p[k])[(size_t)node * 32 + l];
        float v0 = lo16(v);
        float v1 = hi16(v);
        float d = v0 * pw0 + v1 * pw1;
#pragma unroll
        for (int m = 16; m >= 1; m >>= 1) d += __shfl_xor(d, m);
        float s = 1.f / (1.f + expf(-(d * invd + pb0)));  // x_k.pw = invd*(z_k.pw)
        o0 += s * v0;
        o1 += s * v1;
    }
    o0 *= invd;  // back to x-space
    o1 *= invd;
    float mx = fmaxf(o0, o1);
#pragma unroll
    for (int m = 16; m >= 1; m >>= 1) mx = fmaxf(mx, __shfl_xor(mx, m));
    float e = expf(o0 - mx) + expf(o1 - mx);
#pragma unroll
    for (int m = 16; m >= 1; m >>= 1) e += __shfl_xor(e, m);
    float lg = mx + logf(e);
    float2 r = make_float2(o0 - lg, o1 - lg);
    *(float2*)(out + (size_t)node * 64 + 2 * l) = r;
}

// ---------------- launch ----------------
extern "C" void kernel_launch(void* const* d_in, const int* in_sizes, int n_in,
                              void* d_out, int out_size, void* d_ws, size_t ws_size,
                              hipStream_t stream) {
    const float* x  = (const float*)d_in[0];
    const float* W0 = (const float*)d_in[1];
    const float* b0 = (const float*)d_in[2];
    const float* g0 = (const float*)d_in[3];
    const float* be0 = (const float*)d_in[4];
    const float* W1 = (const float*)d_in[5];
    const float* b1 = (const float*)d_in[6];
    const float* g1 = (const float*)d_in[7];
    const float* be1 = (const float*)d_in[8];
    const float* W2 = (const float*)d_in[9];
    const float* b2 = (const float*)d_in[10];
    const float* pw = (const float*)d_in[11];
    const float* pb = (const float*)d_in[12];
    const int* ei = (const int*)d_in[13];
    const int E = in_sizes[13] / 2;
    const int* esrc = ei;
    const int* edst = ei + E;

    char* ws = (char*)d_ws;
    const size_t XKB = (size_t)NN * CC * 2;  // 12,800,000 B per hop buffer
    unsigned short* h0b = (unsigned short*)(ws + 0);          // [N,256] bf16 (pre-BN)
    unsigned short* h1b = (unsigned short*)(ws + 51200000);   // [N,256] bf16 (pre-BN)
    unsigned short* xk[KHOPS + 1];  // z_k buffers, row-major [N][64] bf16
    xk[0] = (unsigned short*)(ws + 0);                         // over h0b (dead after gemm1)
    xk[5] = (unsigned short*)(ws + XKB);
    xk[6] = (unsigned short*)(ws + 2 * XKB);
    xk[7] = (unsigned short*)(ws + 3 * XKB);
    xk[1] = (unsigned short*)(ws + 51200000);                  // over h1b (dead after gemm2)
    xk[2] = (unsigned short*)(ws + 51200000 + XKB);
    xk[3] = (unsigned short*)(ws + 51200000 + 2 * XKB);
    xk[4] = (unsigned short*)(ws + 51200000 + 3 * XKB);
    xk[8] = (unsigned short*)(ws + 102400000);
    xk[9] = (unsigned short*)(ws + 115200000);
    xk[10] = (unsigned short*)(ws + 128000000);

    int*   deg  = (int*)  (ws + 140800000);
    float* dis  = (float*)(ws + 141200000);
    int*   offs = (int*)  (ws + 141600000);   // NN+1 ints
    int*   cur  = (int*)  (ws + 142000064);
    int*   csrc = (int*)  (ws + 142400064);
    float* stats = (float*)(ws + 155200064);  // 2048 f32
    int*   part = (int*)  (ws + 155208256);   // scan partials
    unsigned short* W0t = (unsigned short*)(ws + 155209280);  // [256,512]
    unsigned short* W1t = (unsigned short*)(ws + 155471424);  // [256,256]
    unsigned short* W2t = (unsigned short*)(ws + 155602496);  // [64,256]

    float* sum0 = stats,        *sq0 = stats + 256;
    float* sum1 = stats + 512,  *sq1 = stats + 768;
    float* scale0 = stats + 1024, *shift0 = stats + 1280;
    float* scale1 = stats + 1536, *shift1 = stats + 1792;

    float* out = (float*)d_out;

    const int TPB = 256;
    int ngrid = (NN + TPB - 1) / TPB;
    int wgrid = (NN * 64 + TPB - 1) / TPB;               // one wave per node
    int wgrid2 = (((NN + 1) / 2) * 64 + TPB - 1) / TPB;  // two nodes per wave
    int mtiles = (NN + 127) / 128;                       // 782

    // graph preprocessing (deg/fill XCD-partitioned by dst range)
    k_zero<<<2, 1024, 0, stream>>>(stats, 2048);
    k_deg_init<<<ngrid, TPB, 0, stream>>>(deg, NN);
    k_deg_part<<<128, TPB, 0, stream>>>(edst, E, deg);
    k_dis<<<ngrid, TPB, 0, stream>>>(deg, dis, NN);
    k_scan1<<<SCAN_NB, SCAN_B, 0, stream>>>(deg, part, NN);
    k_scan2<<<1, 64, 0, stream>>>(part, offs + NN, SCAN_NB);
    k_scan3<<<SCAN_NB, SCAN_B, 0, stream>>>(deg, part, offs, cur, NN);
    k_fill_part<<<256, TPB, 0, stream>>>(esrc, edst, E, cur, csrc);

    // weight transpose+cast (tiny)
    k_wt<<<(FF * HH + TPB - 1) / TPB, TPB, 0, stream>>>(W0, W0t, FF, HH);
    k_wt<<<(HH * HH + TPB - 1) / TPB, TPB, 0, stream>>>(W1, W1t, HH, HH);
    k_wt<<<(HH * CC + TPB - 1) / TPB, TPB, 0, stream>>>(W2, W2t, HH, CC);

    // layer 0: x(f32) @ W0 -> h0b (pre-BN bf16) + stats0
    k_gemm_mfma<1, 256, 1, 8, 0, 0><<<dim3(1, mtiles), 512, 0, stream>>>(
        x, W0t, b0, h0b, nullptr, nullptr, nullptr, sum0, sq0, NN, FF, HH);
    k_bnfin<<<1, 256, 0, stream>>>(sum0, sq0, g0, be0, scale0, shift0);

    // layer 1: BN0+ReLU(h0b) @ W1 -> h1b (pre-BN bf16) + stats1 (BN fused in A-read)
    k_gemm_mfma<0, 256, 1, 8, 1, 0><<<dim3(1, mtiles), 512, 0, stream>>>(
        h0b, W1t, b1, h1b, scale0, shift0, nullptr, sum1, sq1, NN, HH, HH);
    k_bnfin<<<1, 256, 0, stream>>>(sum1, sq1, g1, be1, scale1, shift1);

    // layer 2: BN1+ReLU(h1b) @ W2 -> z0 = dis*logits (bf16, row-major)
    k_gemm_mfma<0, 64, 0, 4, 1, 1><<<dim3(1, mtiles), 256, 0, stream>>>(
        h1b, W2t, b2, xk[0], scale1, shift1, dis, nullptr, nullptr, NN, HH, CC);

    // propagation: z_{k+1} = dis2 * (z_k + A z_k)
    for (int k = 0; k < KHOPS; k++)
        k_hop<<<wgrid, TPB, 0, stream>>>(xk[k], xk[k + 1], offs, csrc, dis, NN);

    // fused score + weighted-sum + log-softmax (x_k = z_k / dis)
    XPack xp;
    for (int k = 0; k <= KHOPS; k++) xp.p[k] = xk[k];
    k_finprop<<<wgrid2, TPB, 0, stream>>>(xp, pw, pb, dis, out, NN);
}

// Round 11
// 910.570 us; speedup vs baseline: 2.2313x; 1.1914x over previous
//
#include <hip/hip_runtime.h>
#include <hip/hip_bf16.h>
#include <math.h>

// Problem constants (from reference)
#define NN 100000
#define FF 512
#define HH 256
#define CC 64
#define KHOPS 10
#define BN_EPS 1e-5f
#define NPART 8
#define DRANGE ((NN + NPART - 1) / NPART)  // 12500 dsts per XCD partition

typedef __bf16 bf16x8 __attribute__((ext_vector_type(8)));
typedef float f32x4 __attribute__((ext_vector_type(4)));
typedef unsigned short ushort8v __attribute__((ext_vector_type(8)));

__device__ __forceinline__ unsigned short f2bf(float f) {
    __bf16 b = (__bf16)f;  // v_cvt RNE
    return __builtin_bit_cast(unsigned short, b);
}
__device__ __forceinline__ float bf2f(unsigned short h) {
    unsigned u = ((unsigned)h) << 16;
    return __builtin_bit_cast(float, u);
}
__device__ __forceinline__ float lo16(unsigned u) { return bf2f((unsigned short)(u & 0xFFFF)); }
__device__ __forceinline__ float hi16(unsigned u) { return bf2f((unsigned short)(u >> 16)); }
__device__ __forceinline__ unsigned pk(float a, float b) {
    return ((unsigned)f2bf(b) << 16) | (unsigned)f2bf(a);
}

// async global->LDS, 16B per lane.
typedef __attribute__((address_space(1))) const void g_void;
typedef __attribute__((address_space(3))) void l_void;
__device__ __forceinline__ void gl2lds16(const void* g, void* l) {
    __builtin_amdgcn_global_load_lds((g_void*)g, (l_void*)l, 16, 0, 0);
}

template <int N>
__device__ __forceinline__ void waitcnt_vm() {
    if constexpr (N == 0) asm volatile("s_waitcnt vmcnt(0)" ::: "memory");
    else if constexpr (N == 1) asm volatile("s_waitcnt vmcnt(1)" ::: "memory");
    else if constexpr (N == 2) asm volatile("s_waitcnt vmcnt(2)" ::: "memory");
    else if constexpr (N == 3) asm volatile("s_waitcnt vmcnt(3)" ::: "memory");
    else if constexpr (N == 4) asm volatile("s_waitcnt vmcnt(4)" ::: "memory");
    else if constexpr (N == 5) asm volatile("s_waitcnt vmcnt(5)" ::: "memory");
    else if constexpr (N == 6) asm volatile("s_waitcnt vmcnt(6)" ::: "memory");
    else asm volatile("s_waitcnt vmcnt(8)" ::: "memory");
}

// ---------------- utility kernels ----------------
__global__ void k_zero(float* p, int n) {
    int i = blockIdx.x * blockDim.x + threadIdx.x;
    if (i < n) p[i] = 0.f;
}

__global__ void k_deg_init(int* deg, int n) {
    int i = blockIdx.x * blockDim.x + threadIdx.x;
    if (i < n) deg[i] = 1;  // self-loop
}

// XCD-partitioned degree count: blocks with blockIdx%8==p (XCD p) count dst
// range [p*DRANGE,(p+1)*DRANGE); deg slice (50KB) stays in XCD-p L2.
__global__ __launch_bounds__(256) void k_deg_part(const int* __restrict__ dst, int e,
                                                  int* __restrict__ deg) {
    int part = blockIdx.x & 7;
    int lo = part * DRANGE;
    int hi = min(lo + DRANGE, NN);
    int nsub = gridDim.x >> 3, sub = blockIdx.x >> 3;
    for (int i = sub * blockDim.x + threadIdx.x; i < e; i += nsub * blockDim.x) {
        int d = __builtin_nontemporal_load(&dst[i]);
        if (d >= lo && d < hi) atomicAdd(&deg[d], 1);
    }
}

__global__ void k_dis(const int* __restrict__ deg, float* dis, int n) {
    int i = blockIdx.x * blockDim.x + threadIdx.x;
    if (i < n) dis[i] = rsqrtf((float)deg[i]);
}

// ---------------- hierarchical scan: offs = exclusive prefix of (deg-1) ----------------
#define SCAN_B 1024
#define SCAN_NB ((NN + SCAN_B - 1) / SCAN_B)  // 98

__global__ void k_scan1(const int* __restrict__ deg, int* __restrict__ part, int n) {
    __shared__ int ls[SCAN_B];
    int i = blockIdx.x * SCAN_B + threadIdx.x;
    ls[threadIdx.x] = (i < n) ? deg[i] - 1 : 0;
    __syncthreads();
    for (int d = SCAN_B / 2; d > 0; d >>= 1) {
        if (threadIdx.x < d) ls[threadIdx.x] += ls[threadIdx.x + d];
        __syncthreads();
    }
    if (threadIdx.x == 0) part[blockIdx.x] = ls[0];
}

// parallel exclusive scan of nb (<=128) partials, single 128-thread block
__global__ void k_scan2(int* part, int* offs_last, int nb) {
    __shared__ int ls[128];
    int t = threadIdx.x;
    int v = (t < nb) ? part[t] : 0;
    ls[t] = v;
    __syncthreads();
    for (int d = 1; d < 128; d <<= 1) {
        int u = (t >= d) ? ls[t - d] : 0;
        __syncthreads();
        ls[t] += u;
        __syncthreads();
    }
    if (t < nb) part[t] = ls[t] - v;  // exclusive
    if (t == nb - 1) offs_last[0] = ls[t];  // == E
}

__global__ void k_scan3(const int* __restrict__ deg, const int* __restrict__ part,
                        int* __restrict__ offs, int* __restrict__ cur, int n) {
    __shared__ int ls[SCAN_B];
    int i = blockIdx.x * SCAN_B + threadIdx.x;
    int v = (i < n) ? deg[i] - 1 : 0;
    ls[threadIdx.x] = v;
    __syncthreads();
    for (int d = 1; d < SCAN_B; d <<= 1) {
        int t = (threadIdx.x >= d) ? ls[threadIdx.x - d] : 0;
        __syncthreads();
        ls[threadIdx.x] += t;
        __syncthreads();
    }
    if (i < n) {
        int ex = part[blockIdx.x] + ls[threadIdx.x] - v;
        offs[i] = ex;
        cur[i] = ex;
    }
}

// XCD-partitioned CSR fill: blocks on XCD p handle dst range p -> cursor
// atomics + csrc writes stay in one L2 (no cross-XCD line ping-pong).
__global__ __launch_bounds__(256) void k_fill_part(
    const int* __restrict__ src, const int* __restrict__ dst, int e,
    int* __restrict__ cursor, int* __restrict__ csrc) {
    int part = blockIdx.x & 7;
    int lo = part * DRANGE;
    int hi = min(lo + DRANGE, NN);
    int nsub = gridDim.x >> 3, sub = blockIdx.x >> 3;
    for (int i = sub * blockDim.x + threadIdx.x; i < e; i += nsub * blockDim.x) {
        int d = __builtin_nontemporal_load(&dst[i]);
        if (d >= lo && d < hi) {
            int s = __builtin_nontemporal_load(&src[i]);
            int p = atomicAdd(&cursor[d], 1);
            csrc[p] = s;
        }
    }
}

// transpose+cast weights: Wt[n*K+k] = bf16(W[k*N+n])
__global__ void k_wt(const float* __restrict__ W, unsigned short* __restrict__ Wt,
                     int K, int N) {
    int i = blockIdx.x * blockDim.x + threadIdx.x;
    if (i < K * N) {
        int n = i / K;
        int k = i - n * K;
        Wt[i] = f2bf(W[(size_t)k * N + n]);
    }
}

// ---------------- bf16 MFMA GEMM, pipelined global_load_lds staging -------------
// C = act(A) @ Bt^T + bias.  BM=128, BK=32. Double-buffered LDS; stage(t+2)
// issued after the read-barrier; raw s_barrier + counted vmcnt(S) keeps
// stage(t+1) in flight. FUSEBN applies per-K scale/shift + ReLU to A frags.
// ZSCALE multiplies C rows by dis[row] (z0 = dis * logits).
template <int AF32, int BN_, int STATS, int NW, int FUSEBN, int ZSCALE>
__global__ __launch_bounds__(NW * 64) void k_gemm_mfma(
    const void* __restrict__ Av, const unsigned short* __restrict__ Bt,
    const float* __restrict__ bias, unsigned short* __restrict__ Cb,
    const float* __restrict__ bnscale, const float* __restrict__ bnshift,
    const float* __restrict__ disp,
    float* __restrict__ sum, float* __restrict__ sumsq,
    int M, int K, int Nd) {
    constexpr int NT = NW * 64;
    constexpr int WC = (NW == 8) ? 4 : 2;
    constexpr int PWN = BN_ / WC;
    constexpr int NREP = PWN / 16;
    constexpr int ACH = AF32 ? 8 : 4;
    constexpr int AOPS = 128 * ACH / NT;
    constexpr int BOPS = BN_ * 4 / NT;
    constexpr int S = AOPS + BOPS;  // stage ops per thread
    constexpr int ABUF = AF32 ? 16384 : 8192;
    __shared__ __align__(16) unsigned char Asb[2][ABUF];
    __shared__ __align__(16) unsigned char Bsb[2][BN_ * 64];
    const int tid = threadIdx.x;
    const int lane = tid & 63;
    const int wid = tid >> 6;
    const int wrow = wid / WC, wcol = wid % WC;
    const int row_base = blockIdx.y * 128;
    const int col_base = blockIdx.x * BN_;
    const unsigned char* Abase = (const unsigned char*)Av;
    const size_t arowb = (size_t)K * (AF32 ? 4 : 2);

    f32x4 acc[4][NREP];
#pragma unroll
    for (int m = 0; m < 4; m++)
#pragma unroll
        for (int n = 0; n < NREP; n++)
#pragma unroll
            for (int j = 0; j < 4; j++) acc[m][n][j] = 0.f;

    auto stage = [&](int kt, int buf) {
#pragma unroll
        for (int i = 0; i < AOPS; ++i) {
            int e = i * NT + tid;
            int r = e / ACH;
            int c = e % ACH;
            int cs = AF32 ? (c ^ (r & 7)) : (c ^ ((r >> 1) & 3));
            int grow = row_base + r;
            if (grow > M - 1) grow = M - 1;
            const void* g = Abase + (size_t)grow * arowb + (size_t)kt * (AF32 ? 4 : 2) + (cs << 4);
            gl2lds16(g, Asb[buf] + e * 16);
        }
#pragma unroll
        for (int i = 0; i < BOPS; ++i) {
            int e = i * NT + tid;
            int r = e >> 2, c = e & 3;
            int cs = c ^ ((r >> 1) & 3);
            const void* g = (const unsigned char*)Bt + (size_t)(col_base + r) * (K * 2) +
                            (size_t)kt * 2 + (cs << 4);
            gl2lds16(g, Bsb[buf] + e * 16);
        }
    };

    const int nt = K / 32;
    stage(0, 0);
    if (nt > 1) stage(32, 1);

    for (int t = 0; t < nt; ++t) {
        if (t + 1 < nt) waitcnt_vm<S>();   // stage(t) done; stage(t+1) in flight
        else            waitcnt_vm<0>();
        __builtin_amdgcn_s_barrier();
        const int cur = t & 1;

        f32x4 sc0{}, sc1{}, sh0{}, sh1{};
        if (FUSEBN) {
            int kc = t * 32 + (lane >> 4) * 8;
            sc0 = *(const f32x4*)(bnscale + kc);
            sc1 = *(const f32x4*)(bnscale + kc + 4);
            sh0 = *(const f32x4*)(bnshift + kc);
            sh1 = *(const f32x4*)(bnshift + kc + 4);
        }

        bf16x8 af[4], bfr[NREP];
#pragma unroll
        for (int m = 0; m < 4; ++m) {
            int r = wrow * 64 + m * 16 + (lane & 15);
            if (AF32) {
                int x7 = r & 7;
                int q2 = (lane >> 4) * 2;
                f32x4 f0 = *(const f32x4*)(Asb[cur] + r * 128 + ((q2 ^ x7) << 4));
                f32x4 f1 = *(const f32x4*)(Asb[cur] + r * 128 + (((q2 + 1) ^ x7) << 4));
                bf16x8 a;
                a[0] = (__bf16)f0[0]; a[1] = (__bf16)f0[1]; a[2] = (__bf16)f0[2]; a[3] = (__bf16)f0[3];
                a[4] = (__bf16)f1[0]; a[5] = (__bf16)f1[1]; a[6] = (__bf16)f1[2]; a[7] = (__bf16)f1[3];
                af[m] = a;
            } else {
                int cs = (lane >> 4) ^ ((r >> 1) & 3);
                bf16x8 a = *(const bf16x8*)(Asb[cur] + r * 64 + (cs << 4));
                if (FUSEBN) {
#pragma unroll
                    for (int j = 0; j < 4; ++j) {
                        a[j]     = (__bf16)fmaxf((float)a[j]     * sc0[j] + sh0[j], 0.f);
                        a[j + 4] = (__bf16)fmaxf((float)a[j + 4] * sc1[j] + sh1[j], 0.f);
                    }
                }
                af[m] = a;
            }
        }
#pragma unroll
        for (int n = 0; n < NREP; ++n) {
            int r = wcol * PWN + n * 16 + (lane & 15);
            int cs = (lane >> 4) ^ ((r >> 1) & 3);
            bfr[n] = *(const bf16x8*)(Bsb[cur] + r * 64 + (cs << 4));
        }
#pragma unroll
        for (int m = 0; m < 4; ++m)
#pragma unroll
            for (int n = 0; n < NREP; ++n)
                acc[m][n] = __builtin_amdgcn_mfma_f32_16x16x32_bf16(af[m], bfr[n], acc[m][n], 0, 0, 0);

        __builtin_amdgcn_s_barrier();      // all waves done reading buf[cur]
        if (t + 2 < nt) stage((t + 2) * 32, cur);
    }

    // epilogue: C/D mapping col=lane&15, row=(lane>>4)*4+j
    const int lc = lane & 15;
    const int lr = (lane >> 4) * 4;
#pragma unroll
    for (int m = 0; m < 4; ++m) {
        int gr0 = row_base + wrow * 64 + m * 16 + lr;
#pragma unroll
        for (int n = 0; n < NREP; ++n) {
            int gc = col_base + wcol * PWN + n * 16 + lc;
            float bb = bias[gc];
#pragma unroll
            for (int j = 0; j < 4; ++j) {
                int gr = gr0 + j;
                if (gr < M) {
                    float v = acc[m][n][j] + bb;
                    if (ZSCALE) v *= disp[gr];  // z0 = dis * logits
                    Cb[(size_t)gr * Nd + gc] = f2bf(v);
                }
            }
        }
    }
    if (STATS) {
#pragma unroll
        for (int n = 0; n < NREP; ++n) {
            int gc = col_base + wcol * PWN + n * 16 + lc;
            float bb = bias[gc];
            float s = 0.f, s2 = 0.f;
#pragma unroll
            for (int m = 0; m < 4; ++m) {
                int gr0 = row_base + wrow * 64 + m * 16 + lr;
#pragma unroll
                for (int j = 0; j < 4; ++j) {
                    if (gr0 + j < M) {
                        float v = acc[m][n][j] + bb;
                        s += v;
                        s2 += v * v;
                    }
                }
            }
            s += __shfl_xor(s, 16); s += __shfl_xor(s, 32);
            s2 += __shfl_xor(s2, 16); s2 += __shfl_xor(s2, 32);
            if ((lane >> 4) == 0) {
                atomicAdd(&sum[gc], s);
                atomicAdd(&sumsq[gc], s2);
            }
        }
    }
}

__global__ void k_bnfin(const float* __restrict__ sum, const float* __restrict__ sq,
                        const float* __restrict__ g, const float* __restrict__ be,
                        float* scale, float* shift) {
    int c = threadIdx.x;
    float mu = sum[c] * (1.f / NN);
    float var = sq[c] * (1.f / NN) - mu * mu;
    float sc = g[c] * rsqrtf(var + BN_EPS);
    scale[c] = sc;
    shift[c] = be[c] - mu * sc;
}

// ---------------- propagation (z-form: no edge weights) ----
// z_{k+1}[d] = dis2[d] * (z_k[d] + sum_{s in N(d)} z_k[s]).
// one wave per node; eight 8-lane groups each take every-8th neighbor with
// uint4 (8-channel) loads -> one load inst = 8 cache lines in flight.
__global__ void k_hop(const unsigned short* __restrict__ zin,
                      unsigned short* __restrict__ zout,
                      const int* __restrict__ offs, const int* __restrict__ csrc,
                      const float* __restrict__ dis, int n) {
    int wid = (int)((blockIdx.x * (size_t)blockDim.x + threadIdx.x) >> 6);
    if (wid >= n) return;
    int lane = threadIdx.x & 63;
    int g = lane >> 3;   // group 0..7
    int j = lane & 7;    // 16B slot in row
    const uint4* z16 = (const uint4*)zin;  // row = 8 uint4 (64 bf16)
    float y0 = 0.f, y1 = 0.f, y2 = 0.f, y3 = 0.f, y4 = 0.f, y5 = 0.f, y6 = 0.f, y7 = 0.f;
    if (g == 0) {  // self term z_k[d]
        uint4 v = z16[(size_t)wid * 8 + j];
        y0 = lo16(v.x); y1 = hi16(v.x);
        y2 = lo16(v.y); y3 = hi16(v.y);
        y4 = lo16(v.z); y5 = hi16(v.z);
        y6 = lo16(v.w); y7 = hi16(v.w);
    }
    int p0 = offs[wid], p1 = offs[wid + 1];
    int p = p0 + g;
    for (; p + 8 < p1; p += 16) {
        int sA = __builtin_nontemporal_load(&csrc[p]);
        int sB = __builtin_nontemporal_load(&csrc[p + 8]);
        uint4 vA = z16[(size_t)sA * 8 + j];
        uint4 vB = z16[(size_t)sB * 8 + j];
        y0 += lo16(vA.x); y1 += hi16(vA.x);
        y2 += lo16(vA.y); y3 += hi16(vA.y);
        y4 += lo16(vA.z); y5 += hi16(vA.z);
        y6 += lo16(vA.w); y7 += hi16(vA.w);
        y0 += lo16(vB.x); y1 += hi16(vB.x);
        y2 += lo16(vB.y); y3 += hi16(vB.y);
        y4 += lo16(vB.z); y5 += hi16(vB.z);
        y6 += lo16(vB.w); y7 += hi16(vB.w);
    }
    for (; p < p1; p += 8) {
        int s = __builtin_nontemporal_load(&csrc[p]);
        uint4 v = z16[(size_t)s * 8 + j];
        y0 += lo16(v.x); y1 += hi16(v.x);
        y2 += lo16(v.y); y3 += hi16(v.y);
        y4 += lo16(v.z); y5 += hi16(v.z);
        y6 += lo16(v.w); y7 += hi16(v.w);
    }
    // sum across the 8 groups (lane bits 3..5)
#pragma unroll
    for (int m = 8; m <= 32; m <<= 1) {
        y0 += __shfl_xor(y0, m); y1 += __shfl_xor(y1, m);
        y2 += __shfl_xor(y2, m); y3 += __shfl_xor(y3, m);
        y4 += __shfl_xor(y4, m); y5 += __shfl_xor(y5, m);
        y6 += __shfl_xor(y6, m); y7 += __shfl_xor(y7, m);
    }
    if (g == 0) {
        float dn = dis[wid];
        float d2 = dn * dn;
        uint4 r;
        r.x = pk(d2 * y0, d2 * y1); r.y = pk(d2 * y2, d2 * y3);
        r.z = pk(d2 * y4, d2 * y5); r.w = pk(d2 * y6, d2 * y7);
        ((uint4*)zout)[(size_t)wid * 8 + j] = r;
    }
}

struct XPack { const unsigned short* p[KHOPS + 1]; };

// two nodes per wave (one per 32-lane half); z inputs, x = z/dis.
__global__ void k_finprop(XPack xp, const float* __restrict__ pw,
                          const float* __restrict__ pbp, const float* __restrict__ dis,
                          float* __restrict__ out, int n) {
    int gw = (int)((blockIdx.x * (size_t)blockDim.x + threadIdx.x) >> 6);
    int lane = threadIdx.x & 63;
    int hf = lane >> 5;
    int l = lane & 31;
    int node = gw * 2 + hf;
    if (node >= n) return;
    float pw0 = pw[2 * l], pw1 = pw[2 * l + 1];
    float pb0 = pbp[0];
    float invd = 1.f / dis[node];
    float o0 = 0.f, o1 = 0.f;
#pragma unroll
    for (int k = 0; k <= KHOPS; k++) {
        unsigned v = ((const unsigned*)xp.p[k])[(size_t)node * 32 + l];
        float v0 = lo16(v);
        float v1 = hi16(v);
        float d = v0 * pw0 + v1 * pw1;
#pragma unroll
        for (int m = 16; m >= 1; m >>= 1) d += __shfl_xor(d, m);
        float s = 1.f / (1.f + expf(-(d * invd + pb0)));  // x_k.pw = invd*(z_k.pw)
        o0 += s * v0;
        o1 += s * v1;
    }
    o0 *= invd;  // back to x-space
    o1 *= invd;
    float mx = fmaxf(o0, o1);
#pragma unroll
    for (int m = 16; m >= 1; m >>= 1) mx = fmaxf(mx, __shfl_xor(mx, m));
    float e = expf(o0 - mx) + expf(o1 - mx);
#pragma unroll
    for (int m = 16; m >= 1; m >>= 1) e += __shfl_xor(e, m);
    float lg = mx + logf(e);
    float2 r = make_float2(o0 - lg, o1 - lg);
    *(float2*)(out + (size_t)node * 64 + 2 * l) = r;
}

// ---------------- launch ----------------
extern "C" void kernel_launch(void* const* d_in, const int* in_sizes, int n_in,
                              void* d_out, int out_size, void* d_ws, size_t ws_size,
                              hipStream_t stream) {
    const float* x  = (const float*)d_in[0];
    const float* W0 = (const float*)d_in[1];
    const float* b0 = (const float*)d_in[2];
    const float* g0 = (const float*)d_in[3];
    const float* be0 = (const float*)d_in[4];
    const float* W1 = (const float*)d_in[5];
    const float* b1 = (const float*)d_in[6];
    const float* g1 = (const float*)d_in[7];
    const float* be1 = (const float*)d_in[8];
    const float* W2 = (const float*)d_in[9];
    const float* b2 = (const float*)d_in[10];
    const float* pw = (const float*)d_in[11];
    const float* pb = (const float*)d_in[12];
    const int* ei = (const int*)d_in[13];
    const int E = in_sizes[13] / 2;
    const int* esrc = ei;
    const int* edst = ei + E;

    char* ws = (char*)d_ws;
    const size_t XKB = (size_t)NN * CC * 2;  // 12,800,000 B per hop buffer
    unsigned short* h0b = (unsigned short*)(ws + 0);          // [N,256] bf16 (pre-BN)
    unsigned short* h1b = (unsigned short*)(ws + 51200000);   // [N,256] bf16 (pre-BN)
    unsigned short* xk[KHOPS + 1];  // z_k buffers, row-major [N][64] bf16
    xk[0] = (unsigned short*)(ws + 0);                         // over h0b (dead after gemm1)
    xk[5] = (unsigned short*)(ws + XKB);
    xk[6] = (unsigned short*)(ws + 2 * XKB);
    xk[7] = (unsigned short*)(ws + 3 * XKB);
    xk[1] = (unsigned short*)(ws + 51200000);                  // over h1b (dead after gemm2)
    xk[2] = (unsigned short*)(ws + 51200000 + XKB);
    xk[3] = (unsigned short*)(ws + 51200000 + 2 * XKB);
    xk[4] = (unsigned short*)(ws + 51200000 + 3 * XKB);
    xk[8] = (unsigned short*)(ws + 102400000);
    xk[9] = (unsigned short*)(ws + 115200000);
    xk[10] = (unsigned short*)(ws + 128000000);

    int*   deg  = (int*)  (ws + 140800000);
    float* dis  = (float*)(ws + 141200000);
    int*   offs = (int*)  (ws + 141600000);   // NN+1 ints
    int*   cur  = (int*)  (ws + 142000064);
    int*   csrc = (int*)  (ws + 142400064);
    float* stats = (float*)(ws + 155200064);  // 2048 f32
    int*   part = (int*)  (ws + 155208256);   // scan partials
    unsigned short* W0t = (unsigned short*)(ws + 155209280);  // [256,512]
    unsigned short* W1t = (unsigned short*)(ws + 155471424);  // [256,256]
    unsigned short* W2t = (unsigned short*)(ws + 155602496);  // [64,256]

    float* sum0 = stats,        *sq0 = stats + 256;
    float* sum1 = stats + 512,  *sq1 = stats + 768;
    float* scale0 = stats + 1024, *shift0 = stats + 1280;
    float* scale1 = stats + 1536, *shift1 = stats + 1792;

    float* out = (float*)d_out;

    const int TPB = 256;
    int ngrid = (NN + TPB - 1) / TPB;
    int wgrid = (NN * 64 + TPB - 1) / TPB;               // one wave per node
    int wgrid2 = (((NN + 1) / 2) * 64 + TPB - 1) / TPB;  // two nodes per wave
    int mtiles = (NN + 127) / 128;                       // 782

    // graph preprocessing (deg/fill XCD-partitioned by dst range, full-size grids)
    k_zero<<<2, 1024, 0, stream>>>(stats, 2048);
    k_deg_init<<<ngrid, TPB, 0, stream>>>(deg, NN);
    k_deg_part<<<2048, TPB, 0, stream>>>(edst, E, deg);
    k_dis<<<ngrid, TPB, 0, stream>>>(deg, dis, NN);
    k_scan1<<<SCAN_NB, SCAN_B, 0, stream>>>(deg, part, NN);
    k_scan2<<<1, 128, 0, stream>>>(part, offs + NN, SCAN_NB);
    k_scan3<<<SCAN_NB, SCAN_B, 0, stream>>>(deg, part, offs, cur, NN);
    k_fill_part<<<2048, TPB, 0, stream>>>(esrc, edst, E, cur, csrc);

    // weight transpose+cast (tiny)
    k_wt<<<(FF * HH + TPB - 1) / TPB, TPB, 0, stream>>>(W0, W0t, FF, HH);
    k_wt<<<(HH * HH + TPB - 1) / TPB, TPB, 0, stream>>>(W1, W1t, HH, HH);
    k_wt<<<(HH * CC + TPB - 1) / TPB, TPB, 0, stream>>>(W2, W2t, HH, CC);

    // layer 0: x(f32) @ W0 -> h0b (pre-BN bf16) + stats0
    k_gemm_mfma<1, 256, 1, 8, 0, 0><<<dim3(1, mtiles), 512, 0, stream>>>(
        x, W0t, b0, h0b, nullptr, nullptr, nullptr, sum0, sq0, NN, FF, HH);
    k_bnfin<<<1, 256, 0, stream>>>(sum0, sq0, g0, be0, scale0, shift0);

    // layer 1: BN0+ReLU(h0b) @ W1 -> h1b (pre-BN bf16) + stats1 (BN fused in A-read)
    k_gemm_mfma<0, 256, 1, 8, 1, 0><<<dim3(1, mtiles), 512, 0, stream>>>(
        h0b, W1t, b1, h1b, scale0, shift0, nullptr, sum1, sq1, NN, HH, HH);
    k_bnfin<<<1, 256, 0, stream>>>(sum1, sq1, g1, be1, scale1, shift1);

    // layer 2: BN1+ReLU(h1b) @ W2 -> z0 = dis*logits (bf16, row-major)
    k_gemm_mfma<0, 64, 0, 4, 1, 1><<<dim3(1, mtiles), 256, 0, stream>>>(
        h1b, W2t, b2, xk[0], scale1, shift1, dis, nullptr, nullptr, NN, HH, CC);

    // propagation: z_{k+1} = dis2 * (z_k + A z_k)
    for (int k = 0; k < KHOPS; k++)
        k_hop<<<wgrid, TPB, 0, stream>>>(xk[k], xk[k + 1], offs, csrc, dis, NN);

    // fused score + weighted-sum + log-softmax (x_k = z_k / dis)
    XPack xp;
    for (int k = 0; k <= KHOPS; k++) xp.p[k] = xk[k];
    k_finprop<<<wgrid2, TPB, 0, stream>>>(xp, pw, pb, dis, out, NN);
}

// Round 14
// 898.442 us; speedup vs baseline: 2.2614x; 1.0135x over previous
//
#include <hip/hip_runtime.h>
#include <hip/hip_bf16.h>
#include <math.h>

// Problem constants (from reference)
#define NN 100000
#define FF 512
#define HH 256
#define CC 64
#define KHOPS 10
#define BN_EPS 1e-5f
#define NPART 8
#define DRANGE ((NN + NPART - 1) / NPART)  // 12500 dsts per XCD partition

typedef __bf16 bf16x8 __attribute__((ext_vector_type(8)));
typedef float f32x4 __attribute__((ext_vector_type(4)));
typedef unsigned short ushort8v __attribute__((ext_vector_type(8)));

__device__ __forceinline__ unsigned short f2bf(float f) {
    __bf16 b = (__bf16)f;  // v_cvt RNE
    return __builtin_bit_cast(unsigned short, b);
}
__device__ __forceinline__ float bf2f(unsigned short h) {
    unsigned u = ((unsigned)h) << 16;
    return __builtin_bit_cast(float, u);
}
__device__ __forceinline__ float lo16(unsigned u) { return bf2f((unsigned short)(u & 0xFFFF)); }
__device__ __forceinline__ float hi16(unsigned u) { return bf2f((unsigned short)(u >> 16)); }
__device__ __forceinline__ unsigned pk(float a, float b) {
    return ((unsigned)f2bf(b) << 16) | (unsigned)f2bf(a);
}

// async global->LDS, 16B per lane.
typedef __attribute__((address_space(1))) const void g_void;
typedef __attribute__((address_space(3))) void l_void;
__device__ __forceinline__ void gl2lds16(const void* g, void* l) {
    __builtin_amdgcn_global_load_lds((g_void*)g, (l_void*)l, 16, 0, 0);
}

template <int N>
__device__ __forceinline__ void waitcnt_vm() {
    if constexpr (N == 0) asm volatile("s_waitcnt vmcnt(0)" ::: "memory");
    else if constexpr (N == 1) asm volatile("s_waitcnt vmcnt(1)" ::: "memory");
    else if constexpr (N == 2) asm volatile("s_waitcnt vmcnt(2)" ::: "memory");
    else if constexpr (N == 3) asm volatile("s_waitcnt vmcnt(3)" ::: "memory");
    else if constexpr (N == 4) asm volatile("s_waitcnt vmcnt(4)" ::: "memory");
    else if constexpr (N == 5) asm volatile("s_waitcnt vmcnt(5)" ::: "memory");
    else if constexpr (N == 6) asm volatile("s_waitcnt vmcnt(6)" ::: "memory");
    else asm volatile("s_waitcnt vmcnt(8)" ::: "memory");
}

// ---------------- utility kernels ----------------
__global__ void k_zero(float* p, int n) {
    int i = blockIdx.x * blockDim.x + threadIdx.x;
    if (i < n) p[i] = 0.f;
}

__global__ void k_deg_init(int* deg, int n) {
    int i = blockIdx.x * blockDim.x + threadIdx.x;
    if (i < n) deg[i] = 1;  // self-loop
}

// XCD-partitioned degree count (blockIdx%8 -> XCD p -> dst range p)
__global__ __launch_bounds__(256) void k_deg_part(const int* __restrict__ dst, int e,
                                                  int* __restrict__ deg) {
    int part = blockIdx.x & 7;
    int lo = part * DRANGE;
    int hi = min(lo + DRANGE, NN);
    int nsub = gridDim.x >> 3, sub = blockIdx.x >> 3;
    for (int i = sub * blockDim.x + threadIdx.x; i < e; i += nsub * blockDim.x) {
        int d = __builtin_nontemporal_load(&dst[i]);
        if (d >= lo && d < hi) atomicAdd(&deg[d], 1);
    }
}

__global__ void k_dis(const int* __restrict__ deg, float* dis, int n) {
    int i = blockIdx.x * blockDim.x + threadIdx.x;
    if (i < n) dis[i] = rsqrtf((float)deg[i]);
}

// ---------------- hierarchical scan: offs = exclusive prefix of (deg-1) ----------------
#define SCAN_B 1024
#define SCAN_NB ((NN + SCAN_B - 1) / SCAN_B)  // 98

__global__ void k_scan1(const int* __restrict__ deg, int* __restrict__ part, int n) {
    __shared__ int ls[SCAN_B];
    int i = blockIdx.x * SCAN_B + threadIdx.x;
    ls[threadIdx.x] = (i < n) ? deg[i] - 1 : 0;
    __syncthreads();
    for (int d = SCAN_B / 2; d > 0; d >>= 1) {
        if (threadIdx.x < d) ls[threadIdx.x] += ls[threadIdx.x + d];
        __syncthreads();
    }
    if (threadIdx.x == 0) part[blockIdx.x] = ls[0];
}

// parallel exclusive scan of nb (<=128) partials, single 128-thread block
__global__ void k_scan2(int* part, int* offs_last, int nb) {
    __shared__ int ls[128];
    int t = threadIdx.x;
    int v = (t < nb) ? part[t] : 0;
    ls[t] = v;
    __syncthreads();
    for (int d = 1; d < 128; d <<= 1) {
        int u = (t >= d) ? ls[t - d] : 0;
        __syncthreads();
        ls[t] += u;
        __syncthreads();
    }
    if (t < nb) part[t] = ls[t] - v;  // exclusive
    if (t == nb - 1) offs_last[0] = ls[t];  // == E
}

__global__ void k_scan3(const int* __restrict__ deg, const int* __restrict__ part,
                        int* __restrict__ offs, int* __restrict__ cur, int n) {
    __shared__ int ls[SCAN_B];
    int i = blockIdx.x * SCAN_B + threadIdx.x;
    int v = (i < n) ? deg[i] - 1 : 0;
    ls[threadIdx.x] = v;
    __syncthreads();
    for (int d = 1; d < SCAN_B; d <<= 1) {
        int t = (threadIdx.x >= d) ? ls[threadIdx.x - d] : 0;
        __syncthreads();
        ls[threadIdx.x] += t;
        __syncthreads();
    }
    if (i < n) {
        int ex = part[blockIdx.x] + ls[threadIdx.x] - v;
        offs[i] = ex;
        cur[i] = ex;
    }
}

// XCD-partitioned CSR fill
__global__ __launch_bounds__(256) void k_fill_part(
    const int* __restrict__ src, const int* __restrict__ dst, int e,
    int* __restrict__ cursor, int* __restrict__ csrc) {
    int part = blockIdx.x & 7;
    int lo = part * DRANGE;
    int hi = min(lo + DRANGE, NN);
    int nsub = gridDim.x >> 3, sub = blockIdx.x >> 3;
    for (int i = sub * blockDim.x + threadIdx.x; i < e; i += nsub * blockDim.x) {
        int d = __builtin_nontemporal_load(&dst[i]);
        if (d >= lo && d < hi) {
            int s = __builtin_nontemporal_load(&src[i]);
            int p = atomicAdd(&cursor[d], 1);
            csrc[p] = s;
        }
    }
}

// transpose+cast weights: Wt[n*K+k] = bf16(W[k*N+n])
__global__ void k_wt(const float* __restrict__ W, unsigned short* __restrict__ Wt,
                     int K, int N) {
    int i = blockIdx.x * blockDim.x + threadIdx.x;
    if (i < K * N) {
        int n = i / K;
        int k = i - n * K;
        Wt[i] = f2bf(W[(size_t)k * N + n]);
    }
}

// ---------------- bf16 MFMA GEMM, pipelined global_load_lds staging -------------
// (R11-proven version.) C = act(A) @ Bt^T + bias.  BM=128, BK=32. Double-buffered
// LDS; stage(t+2) issued after the read-barrier; raw s_barrier + counted
// vmcnt(S) keeps stage(t+1) in flight. FUSEBN applies per-K scale/shift + ReLU
// to A frags. ZSCALE multiplies C rows by dis[row] (z0 = dis * logits).
template <int AF32, int BN_, int STATS, int NW, int FUSEBN, int ZSCALE>
__global__ __launch_bounds__(NW * 64) void k_gemm_mfma(
    const void* __restrict__ Av, const unsigned short* __restrict__ Bt,
    const float* __restrict__ bias, unsigned short* __restrict__ Cb,
    const float* __restrict__ bnscale, const float* __restrict__ bnshift,
    const float* __restrict__ disp,
    float* __restrict__ sum, float* __restrict__ sumsq,
    int M, int K, int Nd) {
    constexpr int NT = NW * 64;
    constexpr int WC = (NW == 8) ? 4 : 2;
    constexpr int PWN = BN_ / WC;
    constexpr int NREP = PWN / 16;
    constexpr int ACH = AF32 ? 8 : 4;
    constexpr int AOPS = 128 * ACH / NT;
    constexpr int BOPS = BN_ * 4 / NT;
    constexpr int S = AOPS + BOPS;  // stage ops per thread
    constexpr int ABUF = AF32 ? 16384 : 8192;
    __shared__ __align__(16) unsigned char Asb[2][ABUF];
    __shared__ __align__(16) unsigned char Bsb[2][BN_ * 64];
    const int tid = threadIdx.x;
    const int lane = tid & 63;
    const int wid = tid >> 6;
    const int wrow = wid / WC, wcol = wid % WC;
    const int row_base = blockIdx.y * 128;
    const int col_base = blockIdx.x * BN_;
    const unsigned char* Abase = (const unsigned char*)Av;
    const size_t arowb = (size_t)K * (AF32 ? 4 : 2);

    f32x4 acc[4][NREP];
#pragma unroll
    for (int m = 0; m < 4; m++)
#pragma unroll
        for (int n = 0; n < NREP; n++)
#pragma unroll
            for (int j = 0; j < 4; j++) acc[m][n][j] = 0.f;

    auto stage = [&](int kt, int buf) {
#pragma unroll
        for (int i = 0; i < AOPS; ++i) {
            int e = i * NT + tid;
            int r = e / ACH;
            int c = e % ACH;
            int cs = AF32 ? (c ^ (r & 7)) : (c ^ ((r >> 1) & 3));
            int grow = row_base + r;
            if (grow > M - 1) grow = M - 1;
            const void* g = Abase + (size_t)grow * arowb + (size_t)kt * (AF32 ? 4 : 2) + (cs << 4);
            gl2lds16(g, Asb[buf] + e * 16);
        }
#pragma unroll
        for (int i = 0; i < BOPS; ++i) {
            int e = i * NT + tid;
            int r = e >> 2, c = e & 3;
            int cs = c ^ ((r >> 1) & 3);
            const void* g = (const unsigned char*)Bt + (size_t)(col_base + r) * (K * 2) +
                            (size_t)kt * 2 + (cs << 4);
            gl2lds16(g, Bsb[buf] + e * 16);
        }
    };

    const int nt = K / 32;
    stage(0, 0);
    if (nt > 1) stage(32, 1);

    for (int t = 0; t < nt; ++t) {
        if (t + 1 < nt) waitcnt_vm<S>();   // stage(t) done; stage(t+1) in flight
        else            waitcnt_vm<0>();
        __builtin_amdgcn_s_barrier();
        const int cur = t & 1;

        f32x4 sc0{}, sc1{}, sh0{}, sh1{};
        if (FUSEBN) {
            int kc = t * 32 + (lane >> 4) * 8;
            sc0 = *(const f32x4*)(bnscale + kc);
            sc1 = *(const f32x4*)(bnscale + kc + 4);
            sh0 = *(const f32x4*)(bnshift + kc);
            sh1 = *(const f32x4*)(bnshift + kc + 4);
        }

        bf16x8 af[4], bfr[NREP];
#pragma unroll
        for (int m = 0; m < 4; ++m) {
            int r = wrow * 64 + m * 16 + (lane & 15);
            if (AF32) {
                int x7 = r & 7;
                int q2 = (lane >> 4) * 2;
                f32x4 f0 = *(const f32x4*)(Asb[cur] + r * 128 + ((q2 ^ x7) << 4));
                f32x4 f1 = *(const f32x4*)(Asb[cur] + r * 128 + (((q2 + 1) ^ x7) << 4));
                bf16x8 a;
                a[0] = (__bf16)f0[0]; a[1] = (__bf16)f0[1]; a[2] = (__bf16)f0[2]; a[3] = (__bf16)f0[3];
                a[4] = (__bf16)f1[0]; a[5] = (__bf16)f1[1]; a[6] = (__bf16)f1[2]; a[7] = (__bf16)f1[3];
                af[m] = a;
            } else {
                int cs = (lane >> 4) ^ ((r >> 1) & 3);
                bf16x8 a = *(const bf16x8*)(Asb[cur] + r * 64 + (cs << 4));
                if (FUSEBN) {
#pragma unroll
                    for (int j = 0; j < 4; ++j) {
                        a[j]     = (__bf16)fmaxf((float)a[j]     * sc0[j] + sh0[j], 0.f);
                        a[j + 4] = (__bf16)fmaxf((float)a[j + 4] * sc1[j] + sh1[j], 0.f);
                    }
                }
                af[m] = a;
            }
        }
#pragma unroll
        for (int n = 0; n < NREP; ++n) {
            int r = wcol * PWN + n * 16 + (lane & 15);
            int cs = (lane >> 4) ^ ((r >> 1) & 3);
            bfr[n] = *(const bf16x8*)(Bsb[cur] + r * 64 + (cs << 4));
        }
#pragma unroll
        for (int m = 0; m < 4; ++m)
#pragma unroll
            for (int n = 0; n < NREP; ++n)
                acc[m][n] = __builtin_amdgcn_mfma_f32_16x16x32_bf16(af[m], bfr[n], acc[m][n], 0, 0, 0);

        __builtin_amdgcn_s_barrier();      // all waves done reading buf[cur]
        if (t + 2 < nt) stage((t + 2) * 32, cur);
    }

    // epilogue: C/D mapping col=lane&15, row=(lane>>4)*4+j
    const int lc = lane & 15;
    const int lr = (lane >> 4) * 4;
#pragma unroll
    for (int m = 0; m < 4; ++m) {
        int gr0 = row_base + wrow * 64 + m * 16 + lr;
#pragma unroll
        for (int n = 0; n < NREP; ++n) {
            int gc = col_base + wcol * PWN + n * 16 + lc;
            float bb = bias[gc];
#pragma unroll
            for (int j = 0; j < 4; ++j) {
                int gr = gr0 + j;
                if (gr < M) {
                    float v = acc[m][n][j] + bb;
                    if (ZSCALE) v *= disp[gr];  // z0 = dis * logits
                    Cb[(size_t)gr * Nd + gc] = f2bf(v);
                }
            }
        }
    }
    if (STATS) {
#pragma unroll
        for (int n = 0; n < NREP; ++n) {
            int gc = col_base + wcol * PWN + n * 16 + lc;
            float bb = bias[gc];
            float s = 0.f, s2 = 0.f;
#pragma unroll
            for (int m = 0; m < 4; ++m) {
                int gr0 = row_base + wrow * 64 + m * 16 + lr;
#pragma unroll
                for (int j = 0; j < 4; ++j) {
                    if (gr0 + j < M) {
                        float v = acc[m][n][j] + bb;
                        s += v;
                        s2 += v * v;
                    }
                }
            }
            s += __shfl_xor(s, 16); s += __shfl_xor(s, 32);
            s2 += __shfl_xor(s2, 16); s2 += __shfl_xor(s2, 32);
            if ((lane >> 4) == 0) {
                atomicAdd(&sum[gc], s);
                atomicAdd(&sumsq[gc], s2);
            }
        }
    }
}

__global__ void k_bnfin(const float* __restrict__ sum, const float* __restrict__ sq,
                        const float* __restrict__ g, const float* __restrict__ be,
                        float* scale, float* shift) {
    int c = threadIdx.x;
    float mu = sum[c] * (1.f / NN);
    float var = sq[c] * (1.f / NN) - mu * mu;
    float sc = g[c] * rsqrtf(var + BN_EPS);
    scale[c] = sc;
    shift[c] = be[c] - mu * sc;
}

// ---------------- propagation (z-form, UNIFORM shfl-broadcast) ----------------
// z_{k+1}[d] = dis2[d] * (z_k[d] + sum_{s in N(d)} z_k[s]).
// One wave per node. Lane i preloads csrc[p0+i] (one coalesced load covers up
// to 64 neighbors). ALL __shfl broadcasts execute in the UNIFORM region (all
// 64 lanes active) — ds_bpermute from an inactive lane is undefined, which was
// the R12/R13 bug. Gathers are then fully unrolled and per-lane predicated, so
// up to 8 independent gathers issue back-to-back. deg>64 falls back to the
// strided direct-load loop.
__global__ void k_hop(const unsigned short* __restrict__ zin,
                      unsigned short* __restrict__ zout,
                      const int* __restrict__ offs, const int* __restrict__ csrc,
                      const float* __restrict__ dis, int n) {
    int wid = (int)((blockIdx.x * (size_t)blockDim.x + threadIdx.x) >> 6);
    if (wid >= n) return;
    int lane = threadIdx.x & 63;
    int g = lane >> 3;   // group 0..7
    int j = lane & 7;    // 16B slot in row
    const uint4* z16 = (const uint4*)zin;  // row = 8 uint4 (64 bf16)
    int p0 = offs[wid], p1 = offs[wid + 1];
    int deg = p1 - p0;
    int dcap = min(deg, 64);
    int myidx = (lane < deg) ? __builtin_nontemporal_load(&csrc[p0 + lane]) : 0;

    // uniform region: every lane executes all 8 broadcasts (src lanes 0..63
    // all active here)
    int sidx[8];
#pragma unroll
    for (int r = 0; r < 8; ++r) sidx[r] = __shfl(myidx, r * 8 + g);

    float y0 = 0.f, y1 = 0.f, y2 = 0.f, y3 = 0.f, y4 = 0.f, y5 = 0.f, y6 = 0.f, y7 = 0.f;
    if (g == 0) {  // self term z_k[d]
        uint4 v = z16[(size_t)wid * 8 + j];
        y0 = lo16(v.x); y1 = hi16(v.x);
        y2 = lo16(v.y); y3 = hi16(v.y);
        y4 = lo16(v.z); y5 = hi16(v.z);
        y6 = lo16(v.w); y7 = hi16(v.w);
    }
    // predicated, fully-unrolled gathers (exec-masked loads, no shfl inside)
#pragma unroll
    for (int r = 0; r < 8; ++r) {
        if (r * 8 + g < dcap) {
            uint4 v = z16[(size_t)sidx[r] * 8 + j];
            y0 += lo16(v.x); y1 += hi16(v.x);
            y2 += lo16(v.y); y3 += hi16(v.y);
            y4 += lo16(v.z); y5 += hi16(v.z);
            y6 += lo16(v.w); y7 += hi16(v.w);
        }
    }
    // rare overflow (deg > 64): direct strided loads, no shfl
    for (int p = p0 + 64 + g; p < p1; p += 8) {
        int s = csrc[p];
        uint4 v = z16[(size_t)s * 8 + j];
        y0 += lo16(v.x); y1 += hi16(v.x);
        y2 += lo16(v.y); y3 += hi16(v.y);
        y4 += lo16(v.z); y5 += hi16(v.z);
        y6 += lo16(v.w); y7 += hi16(v.w);
    }
    // sum across the 8 groups (lane bits 3..5) — uniform region again
#pragma unroll
    for (int m = 8; m <= 32; m <<= 1) {
        y0 += __shfl_xor(y0, m); y1 += __shfl_xor(y1, m);
        y2 += __shfl_xor(y2, m); y3 += __shfl_xor(y3, m);
        y4 += __shfl_xor(y4, m); y5 += __shfl_xor(y5, m);
        y6 += __shfl_xor(y6, m); y7 += __shfl_xor(y7, m);
    }
    if (g == 0) {
        float dn = dis[wid];
        float d2 = dn * dn;
        uint4 r;
        r.x = pk(d2 * y0, d2 * y1); r.y = pk(d2 * y2, d2 * y3);
        r.z = pk(d2 * y4, d2 * y5); r.w = pk(d2 * y6, d2 * y7);
        ((uint4*)zout)[(size_t)wid * 8 + j] = r;
    }
}

struct XPack { const unsigned short* p[KHOPS + 1]; };

// two nodes per wave (one per 32-lane half); z inputs, x = z/dis.
__global__ void k_finprop(XPack xp, const float* __restrict__ pw,
                          const float* __restrict__ pbp, const float* __restrict__ dis,
                          float* __restrict__ out, int n) {
    int gw = (int)((blockIdx.x * (size_t)blockDim.x + threadIdx.x) >> 6);
    int lane = threadIdx.x & 63;
    int hf = lane >> 5;
    int l = lane & 31;
    int node = gw * 2 + hf;
    if (node >= n) return;
    float pw0 = pw[2 * l], pw1 = pw[2 * l + 1];
    float pb0 = pbp[0];
    float invd = 1.f / dis[node];
    float o0 = 0.f, o1 = 0.f;
#pragma unroll
    for (int k = 0; k <= KHOPS; k++) {
        unsigned v = ((const unsigned*)xp.p[k])[(size_t)node * 32 + l];
        float v0 = lo16(v);
        float v1 = hi16(v);
        float d = v0 * pw0 + v1 * pw1;
#pragma unroll
        for (int m = 16; m >= 1; m >>= 1) d += __shfl_xor(d, m);
        float s = 1.f / (1.f + expf(-(d * invd + pb0)));  // x_k.pw = invd*(z_k.pw)
        o0 += s * v0;
        o1 += s * v1;
    }
    o0 *= invd;  // back to x-space
    o1 *= invd;
    float mx = fmaxf(o0, o1);
#pragma unroll
    for (int m = 16; m >= 1; m >>= 1) mx = fmaxf(mx, __shfl_xor(mx, m));
    float e = expf(o0 - mx) + expf(o1 - mx);
#pragma unroll
    for (int m = 16; m >= 1; m >>= 1) e += __shfl_xor(e, m);
    float lg = mx + logf(e);
    float2 r = make_float2(o0 - lg, o1 - lg);
    *(float2*)(out + (size_t)node * 64 + 2 * l) = r;
}

// ---------------- launch ----------------
extern "C" void kernel_launch(void* const* d_in, const int* in_sizes, int n_in,
                              void* d_out, int out_size, void* d_ws, size_t ws_size,
                              hipStream_t stream) {
    const float* x  = (const float*)d_in[0];
    const float* W0 = (const float*)d_in[1];
    const float* b0 = (const float*)d_in[2];
    const float* g0 = (const float*)d_in[3];
    const float* be0 = (const float*)d_in[4];
    const float* W1 = (const float*)d_in[5];
    const float* b1 = (const float*)d_in[6];
    const float* g1 = (const float*)d_in[7];
    const float* be1 = (const float*)d_in[8];
    const float* W2 = (const float*)d_in[9];
    const float* b2 = (const float*)d_in[10];
    const float* pw = (const float*)d_in[11];
    const float* pb = (const float*)d_in[12];
    const int* ei = (const int*)d_in[13];
    const int E = in_sizes[13] / 2;
    const int* esrc = ei;
    const int* edst = ei + E;

    char* ws = (char*)d_ws;
    const size_t XKB = (size_t)NN * CC * 2;  // 12,800,000 B per hop buffer
    unsigned short* h0b = (unsigned short*)(ws + 0);          // [N,256] bf16 (pre-BN)
    unsigned short* h1b = (unsigned short*)(ws + 51200000);   // [N,256] bf16 (pre-BN)
    unsigned short* xk[KHOPS + 1];  // z_k buffers, row-major [N][64] bf16
    xk[0] = (unsigned short*)(ws + 0);                         // over h0b (dead after gemm1)
    xk[5] = (unsigned short*)(ws + XKB);
    xk[6] = (unsigned short*)(ws + 2 * XKB);
    xk[7] = (unsigned short*)(ws + 3 * XKB);
    xk[1] = (unsigned short*)(ws + 51200000);                  // over h1b (dead after gemm2)
    xk[2] = (unsigned short*)(ws + 51200000 + XKB);
    xk[3] = (unsigned short*)(ws + 51200000 + 2 * XKB);
    xk[4] = (unsigned short*)(ws + 51200000 + 3 * XKB);
    xk[8] = (unsigned short*)(ws + 102400000);
    xk[9] = (unsigned short*)(ws + 115200000);
    xk[10] = (unsigned short*)(ws + 128000000);

    int*   deg  = (int*)  (ws + 140800000);
    float* dis  = (float*)(ws + 141200000);
    int*   offs = (int*)  (ws + 141600000);   // NN+1 ints
    int*   cur  = (int*)  (ws + 142000064);
    int*   csrc = (int*)  (ws + 142400064);
    float* stats = (float*)(ws + 155200064);  // 2048 f32
    int*   part = (int*)  (ws + 155208256);   // scan partials
    unsigned short* W0t = (unsigned short*)(ws + 155209280);  // [256,512]
    unsigned short* W1t = (unsigned short*)(ws + 155471424);  // [256,256]
    unsigned short* W2t = (unsigned short*)(ws + 155602496);  // [64,256]

    float* sum0 = stats,        *sq0 = stats + 256;
    float* sum1 = stats + 512,  *sq1 = stats + 768;
    float* scale0 = stats + 1024, *shift0 = stats + 1280;
    float* scale1 = stats + 1536, *shift1 = stats + 1792;

    float* out = (float*)d_out;

    const int TPB = 256;
    int ngrid = (NN + TPB - 1) / TPB;
    int wgrid = (NN * 64 + TPB - 1) / TPB;               // one wave per node
    int wgrid2 = (((NN + 1) / 2) * 64 + TPB - 1) / TPB;  // two nodes per wave
    int mtiles = (NN + 127) / 128;                       // 782

    // graph preprocessing (deg/fill XCD-partitioned by dst range)
    k_zero<<<2, 1024, 0, stream>>>(stats, 2048);
    k_deg_init<<<ngrid, TPB, 0, stream>>>(deg, NN);
    k_deg_part<<<2048, TPB, 0, stream>>>(edst, E, deg);
    k_dis<<<ngrid, TPB, 0, stream>>>(deg, dis, NN);
    k_scan1<<<SCAN_NB, SCAN_B, 0, stream>>>(deg, part, NN);
    k_scan2<<<1, 128, 0, stream>>>(part, offs + NN, SCAN_NB);
    k_scan3<<<SCAN_NB, SCAN_B, 0, stream>>>(deg, part, offs, cur, NN);
    k_fill_part<<<2048, TPB, 0, stream>>>(esrc, edst, E, cur, csrc);

    // weight transpose+cast (tiny)
    k_wt<<<(FF * HH + TPB - 1) / TPB, TPB, 0, stream>>>(W0, W0t, FF, HH);
    k_wt<<<(HH * HH + TPB - 1) / TPB, TPB, 0, stream>>>(W1, W1t, HH, HH);
    k_wt<<<(HH * CC + TPB - 1) / TPB, TPB, 0, stream>>>(W2, W2t, HH, CC);

    // layer 0: x(f32) @ W0 -> h0b (pre-BN bf16) + stats0
    k_gemm_mfma<1, 256, 1, 8, 0, 0><<<dim3(1, mtiles), 512, 0, stream>>>(
        x, W0t, b0, h0b, nullptr, nullptr, nullptr, sum0, sq0, NN, FF, HH);
    k_bnfin<<<1, 256, 0, stream>>>(sum0, sq0, g0, be0, scale0, shift0);

    // layer 1: BN0+ReLU(h0b) @ W1 -> h1b (pre-BN bf16) + stats1 (BN fused in A-read)
    k_gemm_mfma<0, 256, 1, 8, 1, 0><<<dim3(1, mtiles), 512, 0, stream>>>(
        h0b, W1t, b1, h1b, scale0, shift0, nullptr, sum1, sq1, NN, HH, HH);
    k_bnfin<<<1, 256, 0, stream>>>(sum1, sq1, g1, be1, scale1, shift1);

    // layer 2: BN1+ReLU(h1b) @ W2 -> z0 = dis*logits (bf16, row-major)
    k_gemm_mfma<0, 64, 0, 4, 1, 1><<<dim3(1, mtiles), 256, 0, stream>>>(
        h1b, W2t, b2, xk[0], scale1, shift1, dis, nullptr, nullptr, NN, HH, CC);

    // propagation: z_{k+1} = dis2 * (z_k + A z_k)
    for (int k = 0; k < KHOPS; k++)
        k_hop<<<wgrid, TPB, 0, stream>>>(xk[k], xk[k + 1], offs, csrc, dis, NN);

    // fused score + weighted-sum + log-softmax (x_k = z_k / dis)
    XPack xp;
    for (int k = 0; k <= KHOPS; k++) xp.p[k] = xk[k];
    k_finprop<<<wgrid2, TPB, 0, stream>>>(xp, pw, pb, dis, out, NN);
}